// Round 2
// baseline (1214.819 us; speedup 1.0000x reference)
//
#include <hip/hip_runtime.h>
#include <hip/hip_bf16.h>

// Swin block: B=32,H=112,W=112,C=96, heads=3, ws=7, shift=3. NTOK=32*256*49
#define NTOK 401408

typedef __attribute__((ext_vector_type(8))) short s8v;   // 8 x bf16 bits
typedef __attribute__((ext_vector_type(4))) float f4v;   // MFMA C/D frag

__device__ __forceinline__ float bs2f(short s) {
  unsigned u = ((unsigned)(unsigned short)s) << 16;
  float f; __builtin_memcpy(&f, &u, 4); return f;
}
__device__ __forceinline__ short f2bs(float f) {
  __hip_bfloat16 b = __float2bfloat16(f);
  return *reinterpret_cast<short*>(&b);
}
__device__ __forceinline__ s8v ld8(const short* p) { return *(const s8v*)p; }
// region id on the SHIFTED image for the attention mask
__device__ __forceinline__ int rgn(int a) { return (a < 105) ? 0 : ((a < 109) ? 1 : 2); }

// in-wave LDS fence: DS pipe is in-order per wave; lgkmcnt(0) makes writes
// visible to same-wave cross-lane reads (and orders read-before-overwrite).
__device__ __forceinline__ void wave_lds_fence() {
  asm volatile("s_waitcnt lgkmcnt(0)" ::: "memory");
  __builtin_amdgcn_sched_barrier(0);
}

// fast GELU: tanh-form, tanh via exp. |err| ~3e-4, below bf16 rounding of h1.
__device__ __forceinline__ float gelu_f(float x) {
  float y = 1.5957691216057308f * x * (1.f + 0.044715f * x * x); // 2*sqrt(2/pi)*x*(...)
  float t = __expf(y);                    // e^{2u}, u = y/2
  float th = 1.f - 2.f / (1.f + t);       // tanh(u); inf/underflow saturate correctly
  return 0.5f * x * (1.f + th);
}

// ---- dual-dtype accessors: logical float array stored as bf16 or fp32 ----
__device__ __forceinline__ void ld8d(const void* base, size_t elem, int isb, float* o) {
  if (isb) {
    s8v v = *(const s8v*)((const short*)base + elem);
    #pragma unroll
    for (int j = 0; j < 8; j++) o[j] = bs2f(v[j]);
  } else {
    const float* f = (const float*)base + elem;
    float4 a = *(const float4*)f;
    float4 b = *(const float4*)(f + 4);
    o[0]=a.x; o[1]=a.y; o[2]=a.z; o[3]=a.w; o[4]=b.x; o[5]=b.y; o[6]=b.z; o[7]=b.w;
  }
}
__device__ __forceinline__ void st8d(void* base, size_t elem, int isb, const float* v) {
  if (isb) {
    s8v o;
    #pragma unroll
    for (int j = 0; j < 8; j++) o[j] = f2bs(v[j]);
    *(s8v*)((short*)base + elem) = o;
  } else {
    float* f = (float*)base + elem;
    float4 a = {v[0], v[1], v[2], v[3]};
    float4 b = {v[4], v[5], v[6], v[7]};
    *(float4*)f = a;
    *(float4*)(f + 4) = b;
  }
}
__device__ __forceinline__ float lddf(const void* base, size_t elem, int isb) {
  return isb ? bs2f(((const short*)base)[elem]) : ((const float*)base)[elem];
}
__device__ __forceinline__ void stdf(void* base, size_t elem, int isb, float v) {
  if (isb) ((short*)base)[elem] = f2bs(v); else ((float*)base)[elem] = v;
}

// ---- bf16 weight-table element offsets inside d_ws (after 8-elem flag slot) ----
#define OQW   0
#define OQB   27648
#define OPW   27936
#define OPB   37152
#define ORPB  37248
#define ON1W  37760
#define ON1B  37856
#define ON2W  37952
#define ON2B  38048
#define OF1W  38144
#define OF1B  75008
#define OF2W  75392
#define OF2B  112256

// ============ prepass: detect input dtype, convert weights to bf16 ==========
__global__ __launch_bounds__(256) void k_detect_convert(
    const void* x,
    const void* qw, const void* qb, const void* pw, const void* pb, const void* rpb,
    const void* n1w, const void* n1b, const void* n2w, const void* n2b,
    const void* f1w, const void* f1b, const void* f2w, const void* f2b,
    int* flag, short* wb)
{
  __shared__ int cnt_sh;
  if (threadIdx.x == 0) cnt_sh = 0;
  __syncthreads();
  const unsigned* xw = (const unsigned*)x;
  int c = 0;
  for (int i = threadIdx.x; i < 1024; i += 256) {
    unsigned e = (xw[i] >> 7) & 0xFFu;      // exponent field of LOW bf16 half
    if (e >= 0x70u && e <= 0x8Fu) c++;
  }
  atomicAdd(&cnt_sh, c);
  __syncthreads();
  const int isb = (cnt_sh > 512) ? 1 : 0;   // bf16 data: ~1024; fp32 mantissa noise: ~128
  if (blockIdx.x == 0 && threadIdx.x == 0) *flag = isb;

  const void* srcs[13] = {qw, qb, pw, pb, rpb, n1w, n1b, n2w, n2b, f1w, f1b, f2w, f2b};
  const int   ns[13]   = {27648, 288, 9216, 96, 507, 96, 96, 96, 96, 36864, 384, 36864, 96};
  const int   offs[13] = {OQW, OQB, OPW, OPB, ORPB, ON1W, ON1B, ON2W, ON2B, OF1W, OF1B, OF2W, OF2B};
  const int gtid = blockIdx.x * 256 + threadIdx.x;
  for (int a = 0; a < 13; a++) {
    const void* s = srcs[a];
    for (int i = gtid; i < ns[a]; i += 64 * 256)
      wb[offs[a] + i] = f2bs(isb ? bs2f(((const short*)s)[i]) : ((const float*)s)[i]);
  }
}

// ================= Kernel A: LN1 + shift/window + QKV + attn + proj =========
// one block per window (8192 blocks), 384 threads = 6 waves.
// Wave pair (h, h+3) owns head h; wave h does row-tiles {0,1}, wave h+3 does
// {2,3}. LDS 44544 B -> 3 blocks/CU x 6 waves = 18 waves/CU (was 9).
// LDS layout (shorts):
//   head h slab at h*5120: Q [64][40] then K [64][40]
//   P [64][72] = 4608 overlays head slab (row-disjoint across the wave pair)
//   V at 15360 + h*2304: [32][72]; reused as O [64][32]
__global__ __launch_bounds__(384, 5) void k_attn_fused(
    const void* __restrict__ xg, const short* __restrict__ wb,
    const int* __restrict__ flag, void* __restrict__ xrout)
{
  __shared__ __align__(16) short smem[22272];

  const int isb = *flag;
  const int wave = threadIdx.x >> 6;
  const int h = (wave >= 3) ? wave - 3 : wave;   // head
  const int rtb = (wave >= 3) ? 2 : 0;           // first owned row-tile
  const int lane = threadIdx.x & 63;
  const int quad = lane >> 4, l15 = lane & 15;
  const int wi = blockIdx.x;
  const int bb = wi >> 8, wp = wi & 255, wh = wp >> 4, ww = wp & 15;

  short* Qh = smem + h * 5120;            // [64][40]
  short* Kh = Qh + 2560;                  // [64][40]
  short* Ph = smem + h * 5120;            // [64][72] overlays head slab
  short* Vh = smem + 15360 + h * 2304;    // [32][72]  (then O as [64][32])

  // LN gamma/beta kept as bf16 (24 VGPR, not 48)
  s8v gw1[3], gb1[3];
  #pragma unroll
  for (int kc = 0; kc < 3; kc++) {
    gw1[kc] = ld8(wb + ON1W + kc * 32 + quad * 8);
    gb1[kc] = ld8(wb + ON1B + kc * 32 + quad * 8);
  }

  // gather + LN1 into A-fragments for the 2 owned row-tiles
  s8v af[2][3];
  #pragma unroll
  for (int t = 0; t < 2; t++) {
    int n = (rtb + t) * 16 + l15; if (n > 48) n = 48;     // pad rows: dup row 48
    int ii = n / 7, jj = n - ii * 7;
    int hi = wh * 7 + ii + 3; if (hi >= 112) hi -= 112;   // roll(-3) gather
    int wj = ww * 7 + jj + 3; if (wj >= 112) wj -= 112;
    size_t rowoff = ((size_t)bb * 12544 + hi * 112 + wj) * 96;
    float v[3][8]; float sm = 0.f, sq = 0.f;
    #pragma unroll
    for (int kc = 0; kc < 3; kc++) {
      ld8d(xg, rowoff + kc * 32 + quad * 8, isb, v[kc]);
      #pragma unroll
      for (int j = 0; j < 8; j++) { sm += v[kc][j]; sq += v[kc][j] * v[kc][j]; }
    }
    sm += __shfl_xor(sm, 16); sm += __shfl_xor(sm, 32);   // reduce across quads
    sq += __shfl_xor(sq, 16); sq += __shfl_xor(sq, 32);
    float mean = sm * (1.f / 96.f);
    float var  = sq * (1.f / 96.f) - mean * mean;
    float rstd = rsqrtf(var + 1e-5f);
    #pragma unroll
    for (int kc = 0; kc < 3; kc++) {
      s8v o;
      #pragma unroll
      for (int j = 0; j < 8; j++)
        o[j] = f2bs((v[kc][j] - mean) * rstd * bs2f(gw1[kc][j]) + bs2f(gb1[kc][j]));
      af[t][kc] = o;
    }
  }

  // QKV gemm: wave pair computes head h's Q,K,V; each wave its 2 row-tiles
  const float qscale = 0.1767766952966369f;  // 32^-0.5 folded into Q
  #pragma unroll
  for (int s = 0; s < 3; s++) {
    #pragma unroll
    for (int nt = 0; nt < 2; nt++) {
      int col = s * 96 + h * 32 + nt * 16 + l15;
      const short* wrow = wb + OQW + (size_t)col * 96;
      s8v b0 = ld8(wrow + quad * 8), b1 = ld8(wrow + 32 + quad * 8), b2 = ld8(wrow + 64 + quad * 8);
      float bias = bs2f(wb[OQB + col]);
      #pragma unroll
      for (int t = 0; t < 2; t++) {
        f4v acc = {0.f, 0.f, 0.f, 0.f};
        acc = __builtin_amdgcn_mfma_f32_16x16x32_bf16(af[t][0], b0, acc, 0, 0, 0);
        acc = __builtin_amdgcn_mfma_f32_16x16x32_bf16(af[t][1], b1, acc, 0, 0, 0);
        acc = __builtin_amdgcn_mfma_f32_16x16x32_bf16(af[t][2], b2, acc, 0, 0, 0);
        #pragma unroll
        for (int r = 0; r < 4; r++) {
          int tok = (rtb + t) * 16 + quad * 4 + r;   // C-layout: row=quad*4+r, col=l15
          float val = acc[r] + bias;
          int cc = nt * 16 + l15;
          if (s == 0)      Qh[tok * 40 + cc] = f2bs(val * qscale);
          else if (s == 1) Kh[tok * 40 + cc] = f2bs(val);
          else             Vh[cc * 72 + tok] = f2bs(val);   // transposed
        }
      }
    }
  }
  __syncthreads();   // (#0) pair-split Q/K/V rows complete

  // frag reads: Q own rows; K,V ALL rows (written by both pair waves)
  s8v qa[2], kb[4], vf[2][2];
  #pragma unroll
  for (int t = 0; t < 2; t++)
    qa[t] = *(const s8v*)&Qh[((rtb + t) * 16 + l15) * 40 + quad * 8];
  #pragma unroll
  for (int nt = 0; nt < 4; nt++)
    kb[nt] = *(const s8v*)&Kh[(nt * 16 + l15) * 40 + quad * 8];
  #pragma unroll
  for (int nt = 0; nt < 2; nt++)
    #pragma unroll
    for (int kc = 0; kc < 2; kc++)
      vf[nt][kc] = *(const s8v*)&Vh[(nt * 16 + l15) * 72 + kc * 32 + quad * 8];
  __syncthreads();   // (#1) all Q/K/V frag reads done before P overlays slab

  // bias/mask geometry per key column
  int crid[4], ci[4], cj[4]; bool cv[4];
  #pragma unroll
  for (int nt = 0; nt < 4; nt++) {
    int col = nt * 16 + l15;
    cv[nt] = (col < 49);
    int ki = col / 7, kj = col - ki * 7;
    ci[nt] = ki; cj[nt] = kj;
    crid[nt] = rgn(wh * 7 + ki) * 3 + rgn(ww * 7 + kj);
  }

  // QK^T + softmax per owned row-tile; write own P rows (pair-disjoint)
  #pragma unroll
  for (int t = 0; t < 2; t++) {
    f4v sc4[4];
    #pragma unroll
    for (int nt = 0; nt < 4; nt++) {
      f4v z = {0.f, 0.f, 0.f, 0.f};
      sc4[nt] = __builtin_amdgcn_mfma_f32_16x16x32_bf16(qa[t], kb[nt], z, 0, 0, 0);
    }
    #pragma unroll
    for (int rr = 0; rr < 4; rr++) {
      int row = (rtb + t) * 16 + quad * 4 + rr;
      bool vr = (row < 49);
      int ri = row / 7, rj = row - ri * 7;
      int rrid = rgn(wh * 7 + ri) * 3 + rgn(ww * 7 + rj);
      float vals[4];
      float m = -1e30f;
      #pragma unroll
      for (int nt = 0; nt < 4; nt++) {
        float sv;
        if (vr && cv[nt]) {
          int bidx = (ri - ci[nt] + 6) * 13 + (rj - cj[nt] + 6);
          float bias = bs2f(wb[ORPB + bidx * 3 + h]);
          sv = sc4[nt][rr] + bias + ((rrid == crid[nt]) ? 0.f : -100.f);
        } else {
          sv = vr ? -1e30f : 0.f;
        }
        vals[nt] = sv;
        m = fmaxf(m, sv);
      }
      #pragma unroll
      for (int o = 1; o < 16; o <<= 1) m = fmaxf(m, __shfl_xor(m, o));
      float sum = 0.f;
      #pragma unroll
      for (int nt = 0; nt < 4; nt++) { vals[nt] = __expf(vals[nt] - m); sum += vals[nt]; }
      #pragma unroll
      for (int o = 1; o < 16; o <<= 1) sum += __shfl_xor(sum, o);
      float inv = 1.f / sum;
      #pragma unroll
      for (int nt = 0; nt < 4; nt++)
        Ph[row * 72 + nt * 16 + l15] = f2bs(vals[nt] * inv);
    }
  }
  wave_lds_fence();   // P rows are per-wave: in-wave fence suffices

  // PV: own row-tiles; O (overlays V, all vf already in regs since before #1)
  s8v pf[2][2];
  #pragma unroll
  for (int t = 0; t < 2; t++)
    #pragma unroll
    for (int kc = 0; kc < 2; kc++)
      pf[t][kc] = *(const s8v*)&Ph[((rtb + t) * 16 + l15) * 72 + kc * 32 + quad * 8];
  short* Oh = Vh;   // [64][32], head's region, rows pair-disjoint
  #pragma unroll
  for (int t = 0; t < 2; t++) {
    #pragma unroll
    for (int nt = 0; nt < 2; nt++) {
      f4v acc = {0.f, 0.f, 0.f, 0.f};
      acc = __builtin_amdgcn_mfma_f32_16x16x32_bf16(pf[t][0], vf[nt][0], acc, 0, 0, 0);
      acc = __builtin_amdgcn_mfma_f32_16x16x32_bf16(pf[t][1], vf[nt][1], acc, 0, 0, 0);
      #pragma unroll
      for (int r = 0; r < 4; r++) {
        int tok = (rtb + t) * 16 + quad * 4 + r;
        Oh[tok * 32 + nt * 16 + l15] = f2bs(acc[r]);
      }
    }
  }
  __syncthreads();   // (#2) O of all heads visible

  // proj: A = O (k = 3 heads x 32); wave computes cols h*32..+31, own rows
  s8v of[2][3];
  #pragma unroll
  for (int t = 0; t < 2; t++)
    #pragma unroll
    for (int kc = 0; kc < 3; kc++)
      of[t][kc] = *(const s8v*)&smem[15360 + kc * 2304 + ((rtb + t) * 16 + l15) * 32 + quad * 8];
  #pragma unroll
  for (int nt = 0; nt < 2; nt++) {
    int col = h * 32 + nt * 16 + l15;
    const short* wrow = wb + OPW + (size_t)col * 96;
    s8v b0 = ld8(wrow + quad * 8), b1 = ld8(wrow + 32 + quad * 8), b2 = ld8(wrow + 64 + quad * 8);
    float bias = bs2f(wb[OPB + col]);
    #pragma unroll
    for (int t = 0; t < 2; t++) {
      f4v acc = {0.f, 0.f, 0.f, 0.f};
      acc = __builtin_amdgcn_mfma_f32_16x16x32_bf16(of[t][0], b0, acc, 0, 0, 0);
      acc = __builtin_amdgcn_mfma_f32_16x16x32_bf16(of[t][1], b1, acc, 0, 0, 0);
      acc = __builtin_amdgcn_mfma_f32_16x16x32_bf16(of[t][2], b2, acc, 0, 0, 0);
      #pragma unroll
      for (int r = 0; r < 4; r++) {
        int tok = (rtb + t) * 16 + quad * 4 + r;
        if (tok < 49) {
          int ii = tok / 7, jj = tok - ii * 7;
          int hi = wh * 7 + ii + 3; if (hi >= 112) hi -= 112;  // reverse + roll(+3)
          int wj = ww * 7 + jj + 3; if (wj >= 112) wj -= 112;
          size_t dest = ((size_t)bb * 12544 + hi * 112 + wj) * 96 + col;
          stdf(xrout, dest, isb, acc[r] + bias);
        }
      }
    }
  }
}

// ================= Kernel B: LN2 + fc1 + GELU + fc2 + residuals =============
// 256 threads = 4 waves, each wave owns 64 rows, fully independent (h_sh is
// per-wave) -> ZERO barriers, in-wave lgkmcnt fences only. fc1/fc2 split into
// two K-halves of 192 so h_sh is [4][16][200] shorts = 25600 B LDS ->
// 6 blocks/CU = 24 waves/CU (was 3 blocks/12 waves at 50176 B). GELU is the
// tanh/exp form (~11 VALU ops vs erff's ~30). VGPR target <=84 for 6/SIMD.
// xr and out ALIAS (d_out): each (row, col-chunk) is read by the same thread
// that overwrites it, rows disjoint across rt/waves/blocks.
__global__ __launch_bounds__(256, 6) void k_mlp(
    const void* xrv, const void* __restrict__ xg, const short* __restrict__ wb,
    const int* __restrict__ flag, void* outv)
{
  __shared__ __align__(16) short h_sh[4][16][200];   // per-wave 16-row, 192-col half

  const int isb = *flag;
  const int wave = threadIdx.x >> 6, lane = threadIdx.x & 63;
  const int quad = lane >> 4, l15 = lane & 15;
  const size_t m0 = (size_t)blockIdx.x * 256 + (size_t)wave * 64;

  // keep LN gamma/beta as bf16 (24 VGPRs, not 48 floats)
  s8v gw[3], gb[3];
  #pragma unroll
  for (int kc = 0; kc < 3; kc++) {
    gw[kc] = ld8(wb + ON2W + kc * 32 + quad * 8);
    gb[kc] = ld8(wb + ON2B + kc * 32 + quad * 8);
  }

  for (int rt = 0; rt < 4; rt++) {
    // ---- LN2 of this tile's 16 rows (row = l15) ----
    size_t ro = (m0 + rt * 16 + l15) * 96;
    float v[3][8]; float sm = 0.f, sq = 0.f;
    #pragma unroll
    for (int kc = 0; kc < 3; kc++) {
      ld8d(xrv, ro + kc * 32 + quad * 8, isb, v[kc]);
      #pragma unroll
      for (int j = 0; j < 8; j++) { sm += v[kc][j]; sq += v[kc][j] * v[kc][j]; }
    }
    sm += __shfl_xor(sm, 16); sm += __shfl_xor(sm, 32);
    sq += __shfl_xor(sq, 16); sq += __shfl_xor(sq, 32);
    float mean = sm * (1.f / 96.f);
    float var  = sq * (1.f / 96.f) - mean * mean;
    float rstd = rsqrtf(var + 1e-5f);
    s8v a2[3];
    #pragma unroll
    for (int kc = 0; kc < 3; kc++) {
      s8v o;
      #pragma unroll
      for (int j = 0; j < 8; j++)
        o[j] = f2bs((v[kc][j] - mean) * rstd * bs2f(gw[kc][j]) + bs2f(gb[kc][j]));
      a2[kc] = o;
    }

    f4v acc6[6];
    #pragma unroll
    for (int nt = 0; nt < 6; nt++) { f4v z = {0.f, 0.f, 0.f, 0.f}; acc6[nt] = z; }

    // ---- two K-halves: fc1(192 cols)+GELU -> h_sh, then fc2 partial ----
    for (int half = 0; half < 2; half++) {
      for (int nt = 0; nt < 12; nt++) {
        int col = half * 192 + nt * 16 + l15;
        const short* wrow = wb + OF1W + (size_t)col * 96;
        s8v b0 = ld8(wrow + quad * 8), b1 = ld8(wrow + 32 + quad * 8), b2 = ld8(wrow + 64 + quad * 8);
        float bias = bs2f(wb[OF1B + col]);
        f4v acc = {0.f, 0.f, 0.f, 0.f};
        acc = __builtin_amdgcn_mfma_f32_16x16x32_bf16(a2[0], b0, acc, 0, 0, 0);
        acc = __builtin_amdgcn_mfma_f32_16x16x32_bf16(a2[1], b1, acc, 0, 0, 0);
        acc = __builtin_amdgcn_mfma_f32_16x16x32_bf16(a2[2], b2, acc, 0, 0, 0);
        #pragma unroll
        for (int r = 0; r < 4; r++)
          h_sh[wave][quad * 4 + r][nt * 16 + l15] = f2bs(gelu_f(acc[r] + bias));
      }
      wave_lds_fence();   // h1 half visible to own wave's cross-lane reads

      // fc2 partial: A from h_sh (per-kc load), B streamed from L2
      for (int kc = 0; kc < 6; kc++) {
        s8v ha = *(const s8v*)&h_sh[wave][l15][kc * 32 + quad * 8];
        #pragma unroll
        for (int nt = 0; nt < 6; nt++) {
          s8v b = ld8(wb + OF2W + (size_t)(nt * 16 + l15) * 384 + half * 192 + kc * 32 + quad * 8);
          acc6[nt] = __builtin_amdgcn_mfma_f32_16x16x32_bf16(ha, b, acc6[nt], 0, 0, 0);
        }
      }
      wave_lds_fence();   // ha reads drained before next half overwrites h_sh
    }

    // ---- transpose acc via per-wave f32 LDS tile [16][100] = 6400 B slice ----
    float* ot = (float*)&h_sh[wave][0][0];
    #pragma unroll
    for (int nt = 0; nt < 6; nt++) {
      float bias = bs2f(wb[OF2B + nt * 16 + l15]);
      #pragma unroll
      for (int r = 0; r < 4; r++)
        ot[(quad * 4 + r) * 100 + nt * 16 + l15] = acc6[nt][r] + bias;
    }
    wave_lds_fence();   // f32 tile visible for cross-lane vector reads

    // ---- vectorized epilogue: thread (quad,l15) owns row l15, 3 8-col chunks.
    // read-before-write on the aliased xr/out chunk happens in-thread.
    size_t grow = m0 + rt * 16 + l15;
    #pragma unroll
    for (int j = 0; j < 3; j++) {
      int c0 = (quad + 4 * j) * 8;
      float vx[8], vr[8], vo[8];
      ld8d(xg,  grow * 96 + c0, isb, vx);
      ld8d(xrv, grow * 96 + c0, isb, vr);
      #pragma unroll
      for (int e = 0; e < 8; e++) vo[e] = ot[l15 * 100 + c0 + e] + vx[e] + vr[e];
      st8d(outv, grow * 96 + c0, isb, vo);
    }
    wave_lds_fence();   // ot reads drained before next rt's fc1 writes (WAR)
  }
}

extern "C" void kernel_launch(void* const* d_in, const int* in_sizes, int n_in,
                              void* d_out, int out_size, void* d_ws, size_t ws_size,
                              hipStream_t stream) {
  int*   flag = (int*)d_ws;
  short* wb   = (short*)d_ws + 8;   // bf16 weight table, byte offset 16

  k_detect_convert<<<64, 256, 0, stream>>>(
      d_in[0],
      d_in[3], d_in[4], d_in[5], d_in[6], d_in[7],
      d_in[1], d_in[2], d_in[8], d_in[9],
      d_in[10], d_in[11], d_in[12], d_in[13],
      flag, wb);
  k_attn_fused<<<32 * 256, 384, 0, stream>>>(d_in[0], wb, flag, d_out);
  k_mlp<<<NTOK / 256, 256, 0, stream>>>(d_out, d_in[0], wb, flag, d_out);
}

// Round 4
// 1032.145 us; speedup vs baseline: 1.1770x; 1.1770x over previous
//
#include <hip/hip_runtime.h>
#include <hip/hip_bf16.h>

// Swin block: B=32,H=112,W=112,C=96, heads=3, ws=7, shift=3. NTOK=32*256*49
#define NTOK 401408

typedef __attribute__((ext_vector_type(8))) short s8v;   // 8 x bf16 bits
typedef __attribute__((ext_vector_type(4))) float f4v;   // MFMA C/D frag

__device__ __forceinline__ float bs2f(short s) {
  unsigned u = ((unsigned)(unsigned short)s) << 16;
  float f; __builtin_memcpy(&f, &u, 4); return f;
}
__device__ __forceinline__ short f2bs(float f) {
  __hip_bfloat16 b = __float2bfloat16(f);
  return *reinterpret_cast<short*>(&b);
}
__device__ __forceinline__ s8v ld8(const short* p) { return *(const s8v*)p; }
// region id on the SHIFTED image for the attention mask
__device__ __forceinline__ int rgn(int a) { return (a < 105) ? 0 : ((a < 109) ? 1 : 2); }

// in-wave LDS fence: DS pipe is in-order per wave; lgkmcnt(0) makes writes
// visible to same-wave cross-lane reads (and orders read-before-overwrite).
__device__ __forceinline__ void wave_lds_fence() {
  asm volatile("s_waitcnt lgkmcnt(0)" ::: "memory");
  __builtin_amdgcn_sched_barrier(0);
}

// fast GELU: tanh-form, tanh via exp. |err| ~3e-4, below bf16 rounding of h1.
__device__ __forceinline__ float gelu_f(float x) {
  float y = 1.5957691216057308f * x * (1.f + 0.044715f * x * x); // 2*sqrt(2/pi)*x*(...)
  float t = __expf(y);                    // e^{2u}, u = y/2
  float th = 1.f - 2.f / (1.f + t);       // tanh(u); inf/underflow saturate correctly
  return 0.5f * x * (1.f + th);
}

// ---- dual-dtype accessors: logical float array stored as bf16 or fp32 ----
__device__ __forceinline__ void ld8d(const void* base, size_t elem, int isb, float* o) {
  if (isb) {
    s8v v = *(const s8v*)((const short*)base + elem);
    #pragma unroll
    for (int j = 0; j < 8; j++) o[j] = bs2f(v[j]);
  } else {
    const float* f = (const float*)base + elem;
    float4 a = *(const float4*)f;
    float4 b = *(const float4*)(f + 4);
    o[0]=a.x; o[1]=a.y; o[2]=a.z; o[3]=a.w; o[4]=b.x; o[5]=b.y; o[6]=b.z; o[7]=b.w;
  }
}
__device__ __forceinline__ void st8d(void* base, size_t elem, int isb, const float* v) {
  if (isb) {
    s8v o;
    #pragma unroll
    for (int j = 0; j < 8; j++) o[j] = f2bs(v[j]);
    *(s8v*)((short*)base + elem) = o;
  } else {
    float* f = (float*)base + elem;
    float4 a = {v[0], v[1], v[2], v[3]};
    float4 b = {v[4], v[5], v[6], v[7]};
    *(float4*)f = a;
    *(float4*)(f + 4) = b;
  }
}
__device__ __forceinline__ float lddf(const void* base, size_t elem, int isb) {
  return isb ? bs2f(((const short*)base)[elem]) : ((const float*)base)[elem];
}
__device__ __forceinline__ void stdf(void* base, size_t elem, int isb, float v) {
  if (isb) ((short*)base)[elem] = f2bs(v); else ((float*)base)[elem] = v;
}

// ---- bf16 weight-table element offsets inside d_ws (after 8-elem flag slot) ----
#define OQW   0
#define OQB   27648
#define OPW   27936
#define OPB   37152
#define ORPB  37248
#define ON1W  37760
#define ON1B  37856
#define ON2W  37952
#define ON2B  38048
#define OF1W  38144
#define OF1B  75008
#define OF2W  75392
#define OF2B  112256

// ============ prepass: detect input dtype, convert weights to bf16 ==========
__global__ __launch_bounds__(256) void k_detect_convert(
    const void* x,
    const void* qw, const void* qb, const void* pw, const void* pb, const void* rpb,
    const void* n1w, const void* n1b, const void* n2w, const void* n2b,
    const void* f1w, const void* f1b, const void* f2w, const void* f2b,
    int* flag, short* wb)
{
  __shared__ int cnt_sh;
  if (threadIdx.x == 0) cnt_sh = 0;
  __syncthreads();
  const unsigned* xw = (const unsigned*)x;
  int c = 0;
  for (int i = threadIdx.x; i < 1024; i += 256) {
    unsigned e = (xw[i] >> 7) & 0xFFu;      // exponent field of LOW bf16 half
    if (e >= 0x70u && e <= 0x8Fu) c++;
  }
  atomicAdd(&cnt_sh, c);
  __syncthreads();
  const int isb = (cnt_sh > 512) ? 1 : 0;   // bf16 data: ~1024; fp32 mantissa noise: ~128
  if (blockIdx.x == 0 && threadIdx.x == 0) *flag = isb;

  const void* srcs[13] = {qw, qb, pw, pb, rpb, n1w, n1b, n2w, n2b, f1w, f1b, f2w, f2b};
  const int   ns[13]   = {27648, 288, 9216, 96, 507, 96, 96, 96, 96, 36864, 384, 36864, 96};
  const int   offs[13] = {OQW, OQB, OPW, OPB, ORPB, ON1W, ON1B, ON2W, ON2B, OF1W, OF1B, OF2W, OF2B};
  const int gtid = blockIdx.x * 256 + threadIdx.x;
  for (int a = 0; a < 13; a++) {
    const void* s = srcs[a];
    for (int i = gtid; i < ns[a]; i += 64 * 256)
      wb[offs[a] + i] = f2bs(isb ? bs2f(((const short*)s)[i]) : ((const float*)s)[i]);
  }
}

// ================= Kernel A: LN1 + shift/window + QKV + attn + proj =========
// (round-1 known-good 192-thread structure)
// one block per window (8192 blocks), 192 threads = 3 waves, wave h = head h.
// LDS 44544 B. LDS layout (shorts):
//   wave h Q/K slab at h*5120: Q [64][40] then K [64][40]  (5120 total)
//   P [64][72] = 4608 overlays the OWN wave's Q/K slab -> per-wave reuse
//   V at 15360 + h*2304: [32][72]; reused as O [64][32]
// Only the proj phase reads other waves' LDS -> single __syncthreads().
__global__ __launch_bounds__(192, 3) void k_attn_fused(
    const void* __restrict__ xg, const short* __restrict__ wb,
    const int* __restrict__ flag, void* __restrict__ xrout)
{
  __shared__ __align__(16) short smem[22272];

  const int isb = *flag;
  const int h = threadIdx.x >> 6;
  const int lane = threadIdx.x & 63;
  const int quad = lane >> 4, l15 = lane & 15;
  const int wi = blockIdx.x;
  const int bb = wi >> 8, wp = wi & 255, wh = wp >> 4, ww = wp & 15;

  short* Qh = smem + h * 5120;            // [64][40]
  short* Kh = Qh + 2560;                  // [64][40]
  short* Ph = smem + h * 5120;            // [64][72] overlays own Q/K
  short* Vh = smem + 15360 + h * 2304;    // [32][72]  (then O as [64][32])

  // LN gamma/beta for this lane's 24 channels
  float gwv[3][8], gbv[3][8];
  #pragma unroll
  for (int kc = 0; kc < 3; kc++) {
    s8v g = ld8(wb + ON1W + kc * 32 + quad * 8);
    s8v t = ld8(wb + ON1B + kc * 32 + quad * 8);
    #pragma unroll
    for (int j = 0; j < 8; j++) { gwv[kc][j] = bs2f(g[j]); gbv[kc][j] = bs2f(t[j]); }
  }

  // gather + LN1 into A-fragments (row = token, k = channel)
  s8v af[4][3];
  #pragma unroll
  for (int rt = 0; rt < 4; rt++) {
    int n = rt * 16 + l15; if (n > 48) n = 48;            // pad rows: dup row 48
    int ii = n / 7, jj = n - ii * 7;
    int hi = wh * 7 + ii + 3; if (hi >= 112) hi -= 112;   // roll(-3) gather
    int wj = ww * 7 + jj + 3; if (wj >= 112) wj -= 112;
    size_t rowoff = ((size_t)bb * 12544 + hi * 112 + wj) * 96;
    float v[3][8]; float sm = 0.f, sq = 0.f;
    #pragma unroll
    for (int kc = 0; kc < 3; kc++) {
      ld8d(xg, rowoff + kc * 32 + quad * 8, isb, v[kc]);
      #pragma unroll
      for (int j = 0; j < 8; j++) { sm += v[kc][j]; sq += v[kc][j] * v[kc][j]; }
    }
    sm += __shfl_xor(sm, 16); sm += __shfl_xor(sm, 32);   // reduce across quads
    sq += __shfl_xor(sq, 16); sq += __shfl_xor(sq, 32);
    float mean = sm * (1.f / 96.f);
    float var  = sq * (1.f / 96.f) - mean * mean;
    float rstd = rsqrtf(var + 1e-5f);
    #pragma unroll
    for (int kc = 0; kc < 3; kc++) {
      s8v o;
      #pragma unroll
      for (int j = 0; j < 8; j++) o[j] = f2bs((v[kc][j] - mean) * rstd * gwv[kc][j] + gbv[kc][j]);
      af[rt][kc] = o;
    }
  }

  // QKV gemm: wave h computes head h's Q,K,V (2 col-tiles each)
  const float qscale = 0.1767766952966369f;  // 32^-0.5 folded into Q
  #pragma unroll
  for (int s = 0; s < 3; s++) {
    #pragma unroll
    for (int nt = 0; nt < 2; nt++) {
      int col = s * 96 + h * 32 + nt * 16 + l15;
      const short* wrow = wb + OQW + (size_t)col * 96;
      s8v b0 = ld8(wrow + quad * 8), b1 = ld8(wrow + 32 + quad * 8), b2 = ld8(wrow + 64 + quad * 8);
      float bias = bs2f(wb[OQB + col]);
      #pragma unroll
      for (int rt = 0; rt < 4; rt++) {
        f4v acc = {0.f, 0.f, 0.f, 0.f};
        acc = __builtin_amdgcn_mfma_f32_16x16x32_bf16(af[rt][0], b0, acc, 0, 0, 0);
        acc = __builtin_amdgcn_mfma_f32_16x16x32_bf16(af[rt][1], b1, acc, 0, 0, 0);
        acc = __builtin_amdgcn_mfma_f32_16x16x32_bf16(af[rt][2], b2, acc, 0, 0, 0);
        #pragma unroll
        for (int r = 0; r < 4; r++) {
          int tok = rt * 16 + quad * 4 + r;          // C-layout: row=quad*4+r, col=l15
          float val = acc[r] + bias;
          int cc = nt * 16 + l15;
          if (s == 0)      Qh[tok * 40 + cc] = f2bs(val * qscale);
          else if (s == 1) Kh[tok * 40 + cc] = f2bs(val);
          else             Vh[cc * 72 + tok] = f2bs(val);   // transposed
        }
      }
    }
  }
  wave_lds_fence();   // Q/K/V stores are per-wave slabs

  s8v qa[4], kb[4], vf[2][2];
  #pragma unroll
  for (int t = 0; t < 4; t++) {
    qa[t] = *(const s8v*)&Qh[(t * 16 + l15) * 40 + quad * 8];
    kb[t] = *(const s8v*)&Kh[(t * 16 + l15) * 40 + quad * 8];
  }
  #pragma unroll
  for (int nt = 0; nt < 2; nt++)
    #pragma unroll
    for (int kc = 0; kc < 2; kc++)
      vf[nt][kc] = *(const s8v*)&Vh[(nt * 16 + l15) * 72 + kc * 32 + quad * 8];

  // bias/mask geometry per key column
  int crid[4], ci[4], cj[4]; bool cv[4];
  #pragma unroll
  for (int nt = 0; nt < 4; nt++) {
    int col = nt * 16 + l15;
    cv[nt] = (col < 49);
    int ki = col / 7, kj = col - ki * 7;
    ci[nt] = ki; cj[nt] = kj;
    crid[nt] = rgn(wh * 7 + ki) * 3 + rgn(ww * 7 + kj);
  }

  // QK^T + softmax per row-tile (sc held only one tile at a time: 16 regs not 64).
  // P overlays OWN wave's Q/K: qa/kb/vf already in registers; DS pipe is
  // in-order per wave so P writes land after the fragment reads. No barrier.
  #pragma unroll
  for (int rt = 0; rt < 4; rt++) {
    f4v sc4[4];
    #pragma unroll
    for (int nt = 0; nt < 4; nt++) {
      f4v z = {0.f, 0.f, 0.f, 0.f};
      sc4[nt] = __builtin_amdgcn_mfma_f32_16x16x32_bf16(qa[rt], kb[nt], z, 0, 0, 0);
    }
    #pragma unroll
    for (int rr = 0; rr < 4; rr++) {
      int row = rt * 16 + quad * 4 + rr;
      bool vr = (row < 49);
      int ri = row / 7, rj = row - ri * 7;
      int rrid = rgn(wh * 7 + ri) * 3 + rgn(ww * 7 + rj);
      float vals[4];
      float m = -1e30f;
      #pragma unroll
      for (int nt = 0; nt < 4; nt++) {
        float sv;
        if (vr && cv[nt]) {
          int bidx = (ri - ci[nt] + 6) * 13 + (rj - cj[nt] + 6);
          float bias = bs2f(wb[ORPB + bidx * 3 + h]);
          sv = sc4[nt][rr] + bias + ((rrid == crid[nt]) ? 0.f : -100.f);
        } else {
          sv = vr ? -1e30f : 0.f;
        }
        vals[nt] = sv;
        m = fmaxf(m, sv);
      }
      #pragma unroll
      for (int o = 1; o < 16; o <<= 1) m = fmaxf(m, __shfl_xor(m, o));
      float sum = 0.f;
      #pragma unroll
      for (int nt = 0; nt < 4; nt++) { vals[nt] = __expf(vals[nt] - m); sum += vals[nt]; }
      #pragma unroll
      for (int o = 1; o < 16; o <<= 1) sum += __shfl_xor(sum, o);
      float inv = 1.f / sum;
      #pragma unroll
      for (int nt = 0; nt < 4; nt++)
        Ph[row * 72 + nt * 16 + l15] = f2bs(vals[nt] * inv);
    }
  }
  wave_lds_fence();   // P per-wave

  // PV
  s8v pf[4][2];
  #pragma unroll
  for (int rt = 0; rt < 4; rt++)
    #pragma unroll
    for (int kc = 0; kc < 2; kc++)
      pf[rt][kc] = *(const s8v*)&Ph[(rt * 16 + l15) * 72 + kc * 32 + quad * 8];
  short* Oh = Vh;   // [64][32], own wave's region
  #pragma unroll
  for (int rt = 0; rt < 4; rt++) {
    #pragma unroll
    for (int nt = 0; nt < 2; nt++) {
      f4v acc = {0.f, 0.f, 0.f, 0.f};
      acc = __builtin_amdgcn_mfma_f32_16x16x32_bf16(pf[rt][0], vf[nt][0], acc, 0, 0, 0);
      acc = __builtin_amdgcn_mfma_f32_16x16x32_bf16(pf[rt][1], vf[nt][1], acc, 0, 0, 0);
      #pragma unroll
      for (int r = 0; r < 4; r++) {
        int tok = rt * 16 + quad * 4 + r;
        Oh[tok * 32 + nt * 16 + l15] = f2bs(acc[r]);
      }
    }
  }
  __syncthreads();   // the ONE true cross-wave barrier: proj reads all heads' O

  // proj: A = O (k = 3 heads x 32), wave h computes out cols h*32..+31
  s8v of[4][3];
  #pragma unroll
  for (int rt = 0; rt < 4; rt++)
    #pragma unroll
    for (int kc = 0; kc < 3; kc++)
      of[rt][kc] = *(const s8v*)&smem[15360 + kc * 2304 + (rt * 16 + l15) * 32 + quad * 8];
  #pragma unroll
  for (int nt = 0; nt < 2; nt++) {
    int col = h * 32 + nt * 16 + l15;
    const short* wrow = wb + OPW + (size_t)col * 96;
    s8v b0 = ld8(wrow + quad * 8), b1 = ld8(wrow + 32 + quad * 8), b2 = ld8(wrow + 64 + quad * 8);
    float bias = bs2f(wb[OPB + col]);
    #pragma unroll
    for (int rt = 0; rt < 4; rt++) {
      f4v acc = {0.f, 0.f, 0.f, 0.f};
      acc = __builtin_amdgcn_mfma_f32_16x16x32_bf16(of[rt][0], b0, acc, 0, 0, 0);
      acc = __builtin_amdgcn_mfma_f32_16x16x32_bf16(of[rt][1], b1, acc, 0, 0, 0);
      acc = __builtin_amdgcn_mfma_f32_16x16x32_bf16(of[rt][2], b2, acc, 0, 0, 0);
      #pragma unroll
      for (int r = 0; r < 4; r++) {
        int tok = rt * 16 + quad * 4 + r;
        if (tok < 49) {
          int ii = tok / 7, jj = tok - ii * 7;
          int hi = wh * 7 + ii + 3; if (hi >= 112) hi -= 112;  // reverse + roll(+3)
          int wj = ww * 7 + jj + 3; if (wj >= 112) wj -= 112;
          size_t dest = ((size_t)bb * 12544 + hi * 112 + wj) * 96 + col;
          stdf(xrout, dest, isb, acc[r] + bias);
        }
      }
    }
  }
}

// ================= Kernel B: LN2 + fc1 + GELU + fc2 + residuals =============
// 256 threads = 4 waves, each wave owns 64 rows, fully independent (h_sh is
// per-wave) -> ZERO barriers, in-wave lgkmcnt fences only. fc1/fc2 split into
// two K-halves of 192 -> h_sh [4][16][200] = 25600 B LDS.
// launch_bounds(256,4): VGPR cap 128 -- round 2's (256,6) cap of 85 caused
// scratch spills (+96MB WRITE, +100MB FETCH). Occupancy target 16 waves/CU.
// LN2 input v[3][8] is CARRIED IN REGISTERS to the epilogue (same thread
// holds the same (row,col) elements in both phases) -> xr is read ONCE,
// eliminating 154 MB of demand traffic and the L2-eviction re-fetch.
// xr and out ALIAS (d_out): read-before-write is in-register now.
__global__ __launch_bounds__(256, 4) void k_mlp(
    const void* xrv, const void* __restrict__ xg, const short* __restrict__ wb,
    const int* __restrict__ flag, void* outv)
{
  __shared__ __align__(16) short h_sh[4][16][200];   // per-wave 16-row, 192-col half

  const int isb = *flag;
  const int wave = threadIdx.x >> 6, lane = threadIdx.x & 63;
  const int quad = lane >> 4, l15 = lane & 15;
  const size_t m0 = (size_t)blockIdx.x * 256 + (size_t)wave * 64;

  // keep LN gamma/beta as bf16 (24 VGPRs, not 48 floats)
  s8v gw[3], gb[3];
  #pragma unroll
  for (int kc = 0; kc < 3; kc++) {
    gw[kc] = ld8(wb + ON2W + kc * 32 + quad * 8);
    gb[kc] = ld8(wb + ON2B + kc * 32 + quad * 8);
  }

  for (int rt = 0; rt < 4; rt++) {
    // ---- LN2 of this tile's 16 rows (row = l15); v[] stays live to epilogue ----
    size_t ro = (m0 + rt * 16 + l15) * 96;
    float v[3][8]; float sm = 0.f, sq = 0.f;
    #pragma unroll
    for (int kc = 0; kc < 3; kc++) {
      ld8d(xrv, ro + kc * 32 + quad * 8, isb, v[kc]);
      #pragma unroll
      for (int j = 0; j < 8; j++) { sm += v[kc][j]; sq += v[kc][j] * v[kc][j]; }
    }
    sm += __shfl_xor(sm, 16); sm += __shfl_xor(sm, 32);
    sq += __shfl_xor(sq, 16); sq += __shfl_xor(sq, 32);
    float mean = sm * (1.f / 96.f);
    float var  = sq * (1.f / 96.f) - mean * mean;
    float rstd = rsqrtf(var + 1e-5f);
    s8v a2[3];
    #pragma unroll
    for (int kc = 0; kc < 3; kc++) {
      s8v o;
      #pragma unroll
      for (int j = 0; j < 8; j++)
        o[j] = f2bs((v[kc][j] - mean) * rstd * bs2f(gw[kc][j]) + bs2f(gb[kc][j]));
      a2[kc] = o;
    }

    f4v acc6[6];
    #pragma unroll
    for (int nt = 0; nt < 6; nt++) { f4v z = {0.f, 0.f, 0.f, 0.f}; acc6[nt] = z; }

    // ---- two K-halves: fc1(192 cols)+GELU -> h_sh, then fc2 partial ----
    for (int half = 0; half < 2; half++) {
      for (int nt = 0; nt < 12; nt++) {
        int col = half * 192 + nt * 16 + l15;
        const short* wrow = wb + OF1W + (size_t)col * 96;
        s8v b0 = ld8(wrow + quad * 8), b1 = ld8(wrow + 32 + quad * 8), b2 = ld8(wrow + 64 + quad * 8);
        float bias = bs2f(wb[OF1B + col]);
        f4v acc = {0.f, 0.f, 0.f, 0.f};
        acc = __builtin_amdgcn_mfma_f32_16x16x32_bf16(a2[0], b0, acc, 0, 0, 0);
        acc = __builtin_amdgcn_mfma_f32_16x16x32_bf16(a2[1], b1, acc, 0, 0, 0);
        acc = __builtin_amdgcn_mfma_f32_16x16x32_bf16(a2[2], b2, acc, 0, 0, 0);
        #pragma unroll
        for (int r = 0; r < 4; r++)
          h_sh[wave][quad * 4 + r][nt * 16 + l15] = f2bs(gelu_f(acc[r] + bias));
      }
      wave_lds_fence();   // h1 half visible to own wave's cross-lane reads

      // fc2 partial: A from h_sh (per-kc load), B streamed from L2
      for (int kc = 0; kc < 6; kc++) {
        s8v ha = *(const s8v*)&h_sh[wave][l15][kc * 32 + quad * 8];
        #pragma unroll
        for (int nt = 0; nt < 6; nt++) {
          s8v b = ld8(wb + OF2W + (size_t)(nt * 16 + l15) * 384 + half * 192 + kc * 32 + quad * 8);
          acc6[nt] = __builtin_amdgcn_mfma_f32_16x16x32_bf16(ha, b, acc6[nt], 0, 0, 0);
        }
      }
      wave_lds_fence();   // ha reads drained before next half overwrites h_sh
    }

    // ---- transpose acc via per-wave f32 LDS tile [16][100] = 6400 B slice ----
    float* ot = (float*)&h_sh[wave][0][0];
    #pragma unroll
    for (int nt = 0; nt < 6; nt++) {
      float bias = bs2f(wb[OF2B + nt * 16 + l15]);
      #pragma unroll
      for (int r = 0; r < 4; r++)
        ot[(quad * 4 + r) * 100 + nt * 16 + l15] = acc6[nt][r] + bias;
    }
    wave_lds_fence();   // f32 tile visible for cross-lane vector reads

    // ---- vectorized epilogue: thread (quad,l15) owns row l15, chunks
    // c0 = j*32 + quad*8 == EXACTLY the elements this thread loaded for LN2,
    // so xr comes from the carried v[j][] registers (no re-read).
    size_t grow = m0 + rt * 16 + l15;
    #pragma unroll
    for (int j = 0; j < 3; j++) {
      int c0 = j * 32 + quad * 8;
      float vx[8], vo[8];
      ld8d(xg, grow * 96 + c0, isb, vx);
      #pragma unroll
      for (int e = 0; e < 8; e++) vo[e] = ot[l15 * 100 + c0 + e] + vx[e] + v[j][e];
      st8d(outv, grow * 96 + c0, isb, vo);
    }
    wave_lds_fence();   // ot reads drained before next rt's fc1 writes (WAR)
  }
}

extern "C" void kernel_launch(void* const* d_in, const int* in_sizes, int n_in,
                              void* d_out, int out_size, void* d_ws, size_t ws_size,
                              hipStream_t stream) {
  int*   flag = (int*)d_ws;
  short* wb   = (short*)d_ws + 8;   // bf16 weight table, byte offset 16

  k_detect_convert<<<64, 256, 0, stream>>>(
      d_in[0],
      d_in[3], d_in[4], d_in[5], d_in[6], d_in[7],
      d_in[1], d_in[2], d_in[8], d_in[9],
      d_in[10], d_in[11], d_in[12], d_in[13],
      flag, wb);
  k_attn_fused<<<32 * 256, 192, 0, stream>>>(d_in[0], wb, flag, d_out);
  k_mlp<<<NTOK / 256, 256, 0, stream>>>(d_out, d_in[0], wb, flag, d_out);
}

// Round 5
// 924.171 us; speedup vs baseline: 1.3145x; 1.1168x over previous
//
#include <hip/hip_runtime.h>
#include <hip/hip_bf16.h>

// Swin block: B=32,H=112,W=112,C=96, heads=3, ws=7, shift=3. NTOK=32*256*49
#define NTOK 401408

typedef __attribute__((ext_vector_type(8))) short s8v;   // 8 x bf16 bits
typedef __attribute__((ext_vector_type(4))) float f4v;   // MFMA C/D frag

__device__ __forceinline__ float bs2f(short s) {
  unsigned u = ((unsigned)(unsigned short)s) << 16;
  float f; __builtin_memcpy(&f, &u, 4); return f;
}
__device__ __forceinline__ short f2bs(float f) {
  __hip_bfloat16 b = __float2bfloat16(f);
  return *reinterpret_cast<short*>(&b);
}
__device__ __forceinline__ s8v ld8(const short* p) { return *(const s8v*)p; }
// region id on the SHIFTED image for the attention mask
__device__ __forceinline__ int rgn(int a) { return (a < 105) ? 0 : ((a < 109) ? 1 : 2); }

// in-wave LDS fence: DS pipe is in-order per wave; lgkmcnt(0) makes writes
// visible to same-wave cross-lane reads (and orders read-before-overwrite).
__device__ __forceinline__ void wave_lds_fence() {
  asm volatile("s_waitcnt lgkmcnt(0)" ::: "memory");
  __builtin_amdgcn_sched_barrier(0);
}

// fast GELU: tanh-form, tanh via exp. |err| ~3e-4, below bf16 rounding of h1.
__device__ __forceinline__ float gelu_f(float x) {
  float y = 1.5957691216057308f * x * (1.f + 0.044715f * x * x); // 2*sqrt(2/pi)*x*(...)
  float t = __expf(y);                    // e^{2u}, u = y/2
  float th = 1.f - 2.f / (1.f + t);       // tanh(u); inf/underflow saturate correctly
  return 0.5f * x * (1.f + th);
}

// ---- dual-dtype accessors: logical float array stored as bf16 or fp32 ----
__device__ __forceinline__ void ld8d(const void* base, size_t elem, int isb, float* o) {
  if (isb) {
    s8v v = *(const s8v*)((const short*)base + elem);
    #pragma unroll
    for (int j = 0; j < 8; j++) o[j] = bs2f(v[j]);
  } else {
    const float* f = (const float*)base + elem;
    float4 a = *(const float4*)f;
    float4 b = *(const float4*)(f + 4);
    o[0]=a.x; o[1]=a.y; o[2]=a.z; o[3]=a.w; o[4]=b.x; o[5]=b.y; o[6]=b.z; o[7]=b.w;
  }
}
__device__ __forceinline__ void st8d(void* base, size_t elem, int isb, const float* v) {
  if (isb) {
    s8v o;
    #pragma unroll
    for (int j = 0; j < 8; j++) o[j] = f2bs(v[j]);
    *(s8v*)((short*)base + elem) = o;
  } else {
    float* f = (float*)base + elem;
    float4 a = {v[0], v[1], v[2], v[3]};
    float4 b = {v[4], v[5], v[6], v[7]};
    *(float4*)f = a;
    *(float4*)(f + 4) = b;
  }
}
__device__ __forceinline__ float lddf(const void* base, size_t elem, int isb) {
  return isb ? bs2f(((const short*)base)[elem]) : ((const float*)base)[elem];
}
__device__ __forceinline__ void stdf(void* base, size_t elem, int isb, float v) {
  if (isb) ((short*)base)[elem] = f2bs(v); else ((float*)base)[elem] = v;
}

// ---- bf16 weight-table element offsets inside d_ws (after 8-elem flag slot) ----
// GEMM weight matrices are stored in MFMA-FRAGMENT order: each (16-col x 32-k)
// tile is 512 contiguous elements laid out as lane*8+j (lane = quad*16+l15,
// reading B[col=tile*16+l15][k = kc*32 + quad*8 + j]). A wave's B-fragment
// load is then ONE coalesced 1KB burst instead of a 16-line gather.
#define OQW   0
#define OQB   27648
#define OPW   27936
#define OPB   37152
#define ORPB  37248
#define ON1W  37760
#define ON1B  37856
#define ON2W  37952
#define ON2B  38048
#define OF1W  38144
#define OF1B  75008
#define OF2W  75392
#define OF2B  112256

// ============ prepass: detect input dtype, convert weights to bf16 ==========
// Swizzles qkv_w/proj_w/fc1_w/fc2_w into fragment order (see above).
__global__ __launch_bounds__(256) void k_detect_convert(
    const void* x,
    const void* qw, const void* qb, const void* pw, const void* pb, const void* rpb,
    const void* n1w, const void* n1b, const void* n2w, const void* n2b,
    const void* f1w, const void* f1b, const void* f2w, const void* f2b,
    int* flag, short* wb)
{
  __shared__ int cnt_sh;
  if (threadIdx.x == 0) cnt_sh = 0;
  __syncthreads();
  const unsigned* xw = (const unsigned*)x;
  int c = 0;
  for (int i = threadIdx.x; i < 1024; i += 256) {
    unsigned e = (xw[i] >> 7) & 0xFFu;      // exponent field of LOW bf16 half
    if (e >= 0x70u && e <= 0x8Fu) c++;
  }
  atomicAdd(&cnt_sh, c);
  __syncthreads();
  const int isb = (cnt_sh > 512) ? 1 : 0;   // bf16 data: ~1024; fp32 mantissa noise: ~128
  if (blockIdx.x == 0 && threadIdx.x == 0) *flag = isb;

  const void* srcs[13] = {qw, qb, pw, pb, rpb, n1w, n1b, n2w, n2b, f1w, f1b, f2w, f2b};
  const int   ns[13]   = {27648, 288, 9216, 96, 507, 96, 96, 96, 96, 36864, 384, 36864, 96};
  const int   offs[13] = {OQW, OQB, OPW, OPB, ORPB, ON1W, ON1B, ON2W, ON2B, OF1W, OF1B, OF2W, OF2B};
  const int gtid = blockIdx.x * 256 + threadIdx.x;
  for (int a = 0; a < 13; a++) {
    const void* s = srcs[a];
    for (int i = gtid; i < ns[a]; i += 64 * 256) {
      float val = isb ? bs2f(((const short*)s)[i]) : ((const float*)s)[i];
      int dst;
      if (a == 0 || a == 2 || a == 9) {
        // [C_out][96] row-major (qkv_w 288x96, proj_w 96x96, fc1_w 384x96)
        int col = i / 96, k = i - col * 96;
        int gt = col >> 4, l = col & 15;
        int kc = k >> 5, q = (k >> 3) & 3, j = k & 7;
        dst = ((gt * 3 + kc) << 9) + ((q * 16 + l) << 3) + j;
      } else if (a == 11) {
        // fc2_w [96][384] row-major
        int col = i / 384, k = i - col * 384;
        int nt = col >> 4, l = col & 15;
        int kt = k >> 5, q = (k >> 3) & 3, j = k & 7;
        dst = ((nt * 12 + kt) << 9) + ((q * 16 + l) << 3) + j;
      } else {
        dst = i;
      }
      wb[offs[a] + dst] = f2bs(val);
    }
  }
}

// ================= Kernel A: LN1 + shift/window + QKV + attn + proj =========
// one block per window (8192 blocks), 192 threads = 3 waves, wave h = head h.
// LDS 44544 B. LDS layout (shorts):
//   wave h Q/K slab at h*5120: Q [64][40] then K [64][40]  (5120 total)
//   P [64][72] = 4608 overlays the OWN wave's Q/K slab -> per-wave reuse
//   V at 15360 + h*2304: [32][72]; reused as O [64][32]
// Only the proj phase reads other waves' LDS -> single __syncthreads().
__global__ __launch_bounds__(192, 3) void k_attn_fused(
    const void* __restrict__ xg, const short* __restrict__ wb,
    const int* __restrict__ flag, void* __restrict__ xrout)
{
  __shared__ __align__(16) short smem[22272];

  const int isb = *flag;
  const int h = threadIdx.x >> 6;
  const int lane = threadIdx.x & 63;
  const int quad = lane >> 4, l15 = lane & 15;
  const int wi = blockIdx.x;
  const int bb = wi >> 8, wp = wi & 255, wh = wp >> 4, ww = wp & 15;

  short* Qh = smem + h * 5120;            // [64][40]
  short* Kh = Qh + 2560;                  // [64][40]
  short* Ph = smem + h * 5120;            // [64][72] overlays own Q/K
  short* Vh = smem + 15360 + h * 2304;    // [32][72]  (then O as [64][32])

  // LN gamma/beta for this lane's 24 channels
  float gwv[3][8], gbv[3][8];
  #pragma unroll
  for (int kc = 0; kc < 3; kc++) {
    s8v g = ld8(wb + ON1W + kc * 32 + quad * 8);
    s8v t = ld8(wb + ON1B + kc * 32 + quad * 8);
    #pragma unroll
    for (int j = 0; j < 8; j++) { gwv[kc][j] = bs2f(g[j]); gbv[kc][j] = bs2f(t[j]); }
  }

  // gather + LN1 into A-fragments (row = token, k = channel)
  s8v af[4][3];
  #pragma unroll
  for (int rt = 0; rt < 4; rt++) {
    int n = rt * 16 + l15; if (n > 48) n = 48;            // pad rows: dup row 48
    int ii = n / 7, jj = n - ii * 7;
    int hi = wh * 7 + ii + 3; if (hi >= 112) hi -= 112;   // roll(-3) gather
    int wj = ww * 7 + jj + 3; if (wj >= 112) wj -= 112;
    size_t rowoff = ((size_t)bb * 12544 + hi * 112 + wj) * 96;
    float v[3][8]; float sm = 0.f, sq = 0.f;
    #pragma unroll
    for (int kc = 0; kc < 3; kc++) {
      ld8d(xg, rowoff + kc * 32 + quad * 8, isb, v[kc]);
      #pragma unroll
      for (int j = 0; j < 8; j++) { sm += v[kc][j]; sq += v[kc][j] * v[kc][j]; }
    }
    sm += __shfl_xor(sm, 16); sm += __shfl_xor(sm, 32);   // reduce across quads
    sq += __shfl_xor(sq, 16); sq += __shfl_xor(sq, 32);
    float mean = sm * (1.f / 96.f);
    float var  = sq * (1.f / 96.f) - mean * mean;
    float rstd = rsqrtf(var + 1e-5f);
    #pragma unroll
    for (int kc = 0; kc < 3; kc++) {
      s8v o;
      #pragma unroll
      for (int j = 0; j < 8; j++) o[j] = f2bs((v[kc][j] - mean) * rstd * gwv[kc][j] + gbv[kc][j]);
      af[rt][kc] = o;
    }
  }

  // QKV gemm: wave h computes head h's Q,K,V (2 col-tiles each)
  // B-fragments are coalesced: one 1KB burst per (tile,kc)
  const float qscale = 0.1767766952966369f;  // 32^-0.5 folded into Q
  #pragma unroll
  for (int s = 0; s < 3; s++) {
    #pragma unroll
    for (int nt = 0; nt < 2; nt++) {
      int col = s * 96 + h * 32 + nt * 16 + l15;
      const short* tb = wb + OQW + (size_t)(s * 6 + h * 2 + nt) * 1536;
      s8v b0 = ld8(tb + lane * 8), b1 = ld8(tb + 512 + lane * 8), b2 = ld8(tb + 1024 + lane * 8);
      float bias = bs2f(wb[OQB + col]);
      #pragma unroll
      for (int rt = 0; rt < 4; rt++) {
        f4v acc = {0.f, 0.f, 0.f, 0.f};
        acc = __builtin_amdgcn_mfma_f32_16x16x32_bf16(af[rt][0], b0, acc, 0, 0, 0);
        acc = __builtin_amdgcn_mfma_f32_16x16x32_bf16(af[rt][1], b1, acc, 0, 0, 0);
        acc = __builtin_amdgcn_mfma_f32_16x16x32_bf16(af[rt][2], b2, acc, 0, 0, 0);
        #pragma unroll
        for (int r = 0; r < 4; r++) {
          int tok = rt * 16 + quad * 4 + r;          // C-layout: row=quad*4+r, col=l15
          float val = acc[r] + bias;
          int cc = nt * 16 + l15;
          if (s == 0)      Qh[tok * 40 + cc] = f2bs(val * qscale);
          else if (s == 1) Kh[tok * 40 + cc] = f2bs(val);
          else             Vh[cc * 72 + tok] = f2bs(val);   // transposed
        }
      }
    }
  }
  wave_lds_fence();   // Q/K/V stores are per-wave slabs

  s8v qa[4], kb[4], vf[2][2];
  #pragma unroll
  for (int t = 0; t < 4; t++) {
    qa[t] = *(const s8v*)&Qh[(t * 16 + l15) * 40 + quad * 8];
    kb[t] = *(const s8v*)&Kh[(t * 16 + l15) * 40 + quad * 8];
  }
  #pragma unroll
  for (int nt = 0; nt < 2; nt++)
    #pragma unroll
    for (int kc = 0; kc < 2; kc++)
      vf[nt][kc] = *(const s8v*)&Vh[(nt * 16 + l15) * 72 + kc * 32 + quad * 8];

  // bias/mask geometry per key column
  int crid[4], ci[4], cj[4]; bool cv[4];
  #pragma unroll
  for (int nt = 0; nt < 4; nt++) {
    int col = nt * 16 + l15;
    cv[nt] = (col < 49);
    int ki = col / 7, kj = col - ki * 7;
    ci[nt] = ki; cj[nt] = kj;
    crid[nt] = rgn(wh * 7 + ki) * 3 + rgn(ww * 7 + kj);
  }

  // QK^T + softmax per row-tile (sc held only one tile at a time: 16 regs not 64).
  // P overlays OWN wave's Q/K: qa/kb/vf already in registers; DS pipe is
  // in-order per wave so P writes land after the fragment reads. No barrier.
  #pragma unroll
  for (int rt = 0; rt < 4; rt++) {
    f4v sc4[4];
    #pragma unroll
    for (int nt = 0; nt < 4; nt++) {
      f4v z = {0.f, 0.f, 0.f, 0.f};
      sc4[nt] = __builtin_amdgcn_mfma_f32_16x16x32_bf16(qa[rt], kb[nt], z, 0, 0, 0);
    }
    #pragma unroll
    for (int rr = 0; rr < 4; rr++) {
      int row = rt * 16 + quad * 4 + rr;
      bool vr = (row < 49);
      int ri = row / 7, rj = row - ri * 7;
      int rrid = rgn(wh * 7 + ri) * 3 + rgn(ww * 7 + rj);
      float vals[4];
      float m = -1e30f;
      #pragma unroll
      for (int nt = 0; nt < 4; nt++) {
        float sv;
        if (vr && cv[nt]) {
          int bidx = (ri - ci[nt] + 6) * 13 + (rj - cj[nt] + 6);
          float bias = bs2f(wb[ORPB + bidx * 3 + h]);
          sv = sc4[nt][rr] + bias + ((rrid == crid[nt]) ? 0.f : -100.f);
        } else {
          sv = vr ? -1e30f : 0.f;
        }
        vals[nt] = sv;
        m = fmaxf(m, sv);
      }
      #pragma unroll
      for (int o = 1; o < 16; o <<= 1) m = fmaxf(m, __shfl_xor(m, o));
      float sum = 0.f;
      #pragma unroll
      for (int nt = 0; nt < 4; nt++) { vals[nt] = __expf(vals[nt] - m); sum += vals[nt]; }
      #pragma unroll
      for (int o = 1; o < 16; o <<= 1) sum += __shfl_xor(sum, o);
      float inv = 1.f / sum;
      #pragma unroll
      for (int nt = 0; nt < 4; nt++)
        Ph[row * 72 + nt * 16 + l15] = f2bs(vals[nt] * inv);
    }
  }
  wave_lds_fence();   // P per-wave

  // PV
  s8v pf[4][2];
  #pragma unroll
  for (int rt = 0; rt < 4; rt++)
    #pragma unroll
    for (int kc = 0; kc < 2; kc++)
      pf[rt][kc] = *(const s8v*)&Ph[(rt * 16 + l15) * 72 + kc * 32 + quad * 8];
  short* Oh = Vh;   // [64][32], own wave's region
  #pragma unroll
  for (int rt = 0; rt < 4; rt++) {
    #pragma unroll
    for (int nt = 0; nt < 2; nt++) {
      f4v acc = {0.f, 0.f, 0.f, 0.f};
      acc = __builtin_amdgcn_mfma_f32_16x16x32_bf16(pf[rt][0], vf[nt][0], acc, 0, 0, 0);
      acc = __builtin_amdgcn_mfma_f32_16x16x32_bf16(pf[rt][1], vf[nt][1], acc, 0, 0, 0);
      #pragma unroll
      for (int r = 0; r < 4; r++) {
        int tok = rt * 16 + quad * 4 + r;
        Oh[tok * 32 + nt * 16 + l15] = f2bs(acc[r]);
      }
    }
  }
  __syncthreads();   // the ONE true cross-wave barrier: proj reads all heads' O

  // proj: A = O (k = 3 heads x 32), wave h computes out cols h*32..+31
  s8v of[4][3];
  #pragma unroll
  for (int rt = 0; rt < 4; rt++)
    #pragma unroll
    for (int kc = 0; kc < 3; kc++)
      of[rt][kc] = *(const s8v*)&smem[15360 + kc * 2304 + (rt * 16 + l15) * 32 + quad * 8];
  #pragma unroll
  for (int nt = 0; nt < 2; nt++) {
    int col = h * 32 + nt * 16 + l15;
    const short* tb = wb + OPW + (size_t)(h * 2 + nt) * 1536;
    s8v b0 = ld8(tb + lane * 8), b1 = ld8(tb + 512 + lane * 8), b2 = ld8(tb + 1024 + lane * 8);
    float bias = bs2f(wb[OPB + col]);
    #pragma unroll
    for (int rt = 0; rt < 4; rt++) {
      f4v acc = {0.f, 0.f, 0.f, 0.f};
      acc = __builtin_amdgcn_mfma_f32_16x16x32_bf16(of[rt][0], b0, acc, 0, 0, 0);
      acc = __builtin_amdgcn_mfma_f32_16x16x32_bf16(of[rt][1], b1, acc, 0, 0, 0);
      acc = __builtin_amdgcn_mfma_f32_16x16x32_bf16(of[rt][2], b2, acc, 0, 0, 0);
      #pragma unroll
      for (int r = 0; r < 4; r++) {
        int tok = rt * 16 + quad * 4 + r;
        if (tok < 49) {
          int ii = tok / 7, jj = tok - ii * 7;
          int hi = wh * 7 + ii + 3; if (hi >= 112) hi -= 112;  // reverse + roll(+3)
          int wj = ww * 7 + jj + 3; if (wj >= 112) wj -= 112;
          size_t dest = ((size_t)bb * 12544 + hi * 112 + wj) * 96 + col;
          stdf(xrout, dest, isb, acc[r] + bias);
        }
      }
    }
  }
}

// ================= Kernel B: LN2 + fc1 + GELU + fc2 + residuals =============
// 256 threads = 4 waves, each wave owns 64 rows, fully independent (h_sh is
// per-wave) -> ZERO barriers, in-wave lgkmcnt fences only. fc1/fc2 split into
// two K-halves of 192 -> h_sh [4][16][200] = 25600 B LDS.
// launch_bounds(256,4): VGPR cap 128 (no spill; (256,6)'s cap 85 spilled).
// All weight B-fragments are coalesced 1KB bursts (fragment-order wb).
// LN2 input v[3][8] carried in registers to the epilogue -> xr read once.
// xr and out ALIAS (d_out): read-before-write is in-register.
__global__ __launch_bounds__(256, 4) void k_mlp(
    const void* xrv, const void* __restrict__ xg, const short* __restrict__ wb,
    const int* __restrict__ flag, void* outv)
{
  __shared__ __align__(16) short h_sh[4][16][200];   // per-wave 16-row, 192-col half

  const int isb = *flag;
  const int wave = threadIdx.x >> 6, lane = threadIdx.x & 63;
  const int quad = lane >> 4, l15 = lane & 15;
  const size_t m0 = (size_t)blockIdx.x * 256 + (size_t)wave * 64;

  // keep LN gamma/beta as bf16 (24 VGPRs, not 48 floats)
  s8v gw[3], gb[3];
  #pragma unroll
  for (int kc = 0; kc < 3; kc++) {
    gw[kc] = ld8(wb + ON2W + kc * 32 + quad * 8);
    gb[kc] = ld8(wb + ON2B + kc * 32 + quad * 8);
  }

  for (int rt = 0; rt < 4; rt++) {
    // ---- LN2 of this tile's 16 rows (row = l15); v[] stays live to epilogue ----
    size_t ro = (m0 + rt * 16 + l15) * 96;
    float v[3][8]; float sm = 0.f, sq = 0.f;
    #pragma unroll
    for (int kc = 0; kc < 3; kc++) {
      ld8d(xrv, ro + kc * 32 + quad * 8, isb, v[kc]);
      #pragma unroll
      for (int j = 0; j < 8; j++) { sm += v[kc][j]; sq += v[kc][j] * v[kc][j]; }
    }
    sm += __shfl_xor(sm, 16); sm += __shfl_xor(sm, 32);
    sq += __shfl_xor(sq, 16); sq += __shfl_xor(sq, 32);
    float mean = sm * (1.f / 96.f);
    float var  = sq * (1.f / 96.f) - mean * mean;
    float rstd = rsqrtf(var + 1e-5f);
    s8v a2[3];
    #pragma unroll
    for (int kc = 0; kc < 3; kc++) {
      s8v o;
      #pragma unroll
      for (int j = 0; j < 8; j++)
        o[j] = f2bs((v[kc][j] - mean) * rstd * bs2f(gw[kc][j]) + bs2f(gb[kc][j]));
      a2[kc] = o;
    }

    f4v acc6[6];
    #pragma unroll
    for (int nt = 0; nt < 6; nt++) { f4v z = {0.f, 0.f, 0.f, 0.f}; acc6[nt] = z; }

    // ---- two K-halves: fc1(192 cols)+GELU -> h_sh, then fc2 partial ----
    for (int half = 0; half < 2; half++) {
      for (int nt = 0; nt < 12; nt++) {
        int col = half * 192 + nt * 16 + l15;
        const short* tb = wb + OF1W + (size_t)(half * 12 + nt) * 1536;
        s8v b0 = ld8(tb + lane * 8), b1 = ld8(tb + 512 + lane * 8), b2 = ld8(tb + 1024 + lane * 8);
        float bias = bs2f(wb[OF1B + col]);
        f4v acc = {0.f, 0.f, 0.f, 0.f};
        acc = __builtin_amdgcn_mfma_f32_16x16x32_bf16(a2[0], b0, acc, 0, 0, 0);
        acc = __builtin_amdgcn_mfma_f32_16x16x32_bf16(a2[1], b1, acc, 0, 0, 0);
        acc = __builtin_amdgcn_mfma_f32_16x16x32_bf16(a2[2], b2, acc, 0, 0, 0);
        #pragma unroll
        for (int r = 0; r < 4; r++)
          h_sh[wave][quad * 4 + r][nt * 16 + l15] = f2bs(gelu_f(acc[r] + bias));
      }
      wave_lds_fence();   // h1 half visible to own wave's cross-lane reads

      // fc2 partial: A from h_sh (per-kc load), B coalesced from L2
      for (int kc = 0; kc < 6; kc++) {
        s8v ha = *(const s8v*)&h_sh[wave][l15][kc * 32 + quad * 8];
        #pragma unroll
        for (int nt = 0; nt < 6; nt++) {
          s8v b = ld8(wb + OF2W + (size_t)(nt * 12 + half * 6 + kc) * 512 + lane * 8);
          acc6[nt] = __builtin_amdgcn_mfma_f32_16x16x32_bf16(ha, b, acc6[nt], 0, 0, 0);
        }
      }
      wave_lds_fence();   // ha reads drained before next half overwrites h_sh
    }

    // ---- transpose acc via per-wave f32 LDS tile [16][100] = 6400 B slice ----
    float* ot = (float*)&h_sh[wave][0][0];
    #pragma unroll
    for (int nt = 0; nt < 6; nt++) {
      float bias = bs2f(wb[OF2B + nt * 16 + l15]);
      #pragma unroll
      for (int r = 0; r < 4; r++)
        ot[(quad * 4 + r) * 100 + nt * 16 + l15] = acc6[nt][r] + bias;
    }
    wave_lds_fence();   // f32 tile visible for cross-lane vector reads

    // ---- vectorized epilogue: thread (quad,l15) owns row l15, chunks
    // c0 = j*32 + quad*8 == EXACTLY the elements this thread loaded for LN2,
    // so xr comes from the carried v[j][] registers (no re-read).
    size_t grow = m0 + rt * 16 + l15;
    #pragma unroll
    for (int j = 0; j < 3; j++) {
      int c0 = j * 32 + quad * 8;
      float vx[8], vo[8];
      ld8d(xg, grow * 96 + c0, isb, vx);
      #pragma unroll
      for (int e = 0; e < 8; e++) vo[e] = ot[l15 * 100 + c0 + e] + vx[e] + v[j][e];
      st8d(outv, grow * 96 + c0, isb, vo);
    }
    wave_lds_fence();   // ot reads drained before next rt's fc1 writes (WAR)
  }
}

extern "C" void kernel_launch(void* const* d_in, const int* in_sizes, int n_in,
                              void* d_out, int out_size, void* d_ws, size_t ws_size,
                              hipStream_t stream) {
  int*   flag = (int*)d_ws;
  short* wb   = (short*)d_ws + 8;   // bf16 weight table, byte offset 16

  k_detect_convert<<<64, 256, 0, stream>>>(
      d_in[0],
      d_in[3], d_in[4], d_in[5], d_in[6], d_in[7],
      d_in[1], d_in[2], d_in[8], d_in[9],
      d_in[10], d_in[11], d_in[12], d_in[13],
      flag, wb);
  k_attn_fused<<<32 * 256, 192, 0, stream>>>(d_in[0], wb, flag, d_out);
  k_mlp<<<NTOK / 256, 256, 0, stream>>>(d_out, d_in[0], wb, flag, d_out);
}

// Round 6
// 857.211 us; speedup vs baseline: 1.4172x; 1.0781x over previous
//
#include <hip/hip_runtime.h>
#include <hip/hip_bf16.h>

// Swin block: B=32,H=112,W=112,C=96, heads=3, ws=7, shift=3. NTOK=32*256*49
#define NTOK 401408

typedef __attribute__((ext_vector_type(8))) short s8v;   // 8 x bf16 bits
typedef __attribute__((ext_vector_type(4))) float f4v;   // MFMA C/D frag

__device__ __forceinline__ float bs2f(short s) {
  unsigned u = ((unsigned)(unsigned short)s) << 16;
  float f; __builtin_memcpy(&f, &u, 4); return f;
}
__device__ __forceinline__ short f2bs(float f) {
  __hip_bfloat16 b = __float2bfloat16(f);
  return *reinterpret_cast<short*>(&b);
}
__device__ __forceinline__ s8v ld8(const short* p) { return *(const s8v*)p; }
// region id on the SHIFTED image for the attention mask
__device__ __forceinline__ int rgn(int a) { return (a < 105) ? 0 : ((a < 109) ? 1 : 2); }

// in-wave LDS fence: DS pipe is in-order per wave; lgkmcnt(0) makes writes
// visible to same-wave cross-lane reads (and orders read-before-overwrite).
__device__ __forceinline__ void wave_lds_fence() {
  asm volatile("s_waitcnt lgkmcnt(0)" ::: "memory");
  __builtin_amdgcn_sched_barrier(0);
}

// fast GELU: tanh-form, tanh via exp. |err| ~3e-4, below bf16 rounding of h1.
__device__ __forceinline__ float gelu_f(float x) {
  float y = 1.5957691216057308f * x * (1.f + 0.044715f * x * x); // 2*sqrt(2/pi)*x*(...)
  float t = __expf(y);                    // e^{2u}, u = y/2
  float th = 1.f - 2.f / (1.f + t);       // tanh(u); inf/underflow saturate correctly
  return 0.5f * x * (1.f + th);
}

// ---- dual-dtype accessors: logical float array stored as bf16 or fp32 ----
__device__ __forceinline__ void ld8d(const void* base, size_t elem, int isb, float* o) {
  if (isb) {
    s8v v = *(const s8v*)((const short*)base + elem);
    #pragma unroll
    for (int j = 0; j < 8; j++) o[j] = bs2f(v[j]);
  } else {
    const float* f = (const float*)base + elem;
    float4 a = *(const float4*)f;
    float4 b = *(const float4*)(f + 4);
    o[0]=a.x; o[1]=a.y; o[2]=a.z; o[3]=a.w; o[4]=b.x; o[5]=b.y; o[6]=b.z; o[7]=b.w;
  }
}
__device__ __forceinline__ void st8d(void* base, size_t elem, int isb, const float* v) {
  if (isb) {
    s8v o;
    #pragma unroll
    for (int j = 0; j < 8; j++) o[j] = f2bs(v[j]);
    *(s8v*)((short*)base + elem) = o;
  } else {
    float* f = (float*)base + elem;
    float4 a = {v[0], v[1], v[2], v[3]};
    float4 b = {v[4], v[5], v[6], v[7]};
    *(float4*)f = a;
    *(float4*)(f + 4) = b;
  }
}
__device__ __forceinline__ void stdf(void* base, size_t elem, int isb, float v) {
  if (isb) ((short*)base)[elem] = f2bs(v); else ((float*)base)[elem] = v;
}

// ---- bf16 xr intermediate, packed inside d_out (dtype-dependent layout) ----
// isb=0: out rows are 384B fp32 slots; xr row i = 96 bf16 in the FIRST 192B of
//   slot i. Safe: each k_mlp wave reads its rows' xr (top of rt iter) before it
//   writes those rows' out (bottom of same iter); rows disjoint across
//   waves/blocks; k_attn completes before k_mlp launches.
// isb=1: out is bf16 in the first NTOK*96 shorts; xr lives at [NTOK*96, ...) --
//   fully disjoint.
__device__ __forceinline__ size_t xr_idx(size_t row, int col, int isb) {
  return isb ? ((size_t)NTOK * 96 + row * 96 + col) : (row * 192 + col);
}

// ---- bf16 weight-table element offsets inside d_ws (after 8-elem flag slot) ----
// GEMM weights in MFMA-fragment order (16-col x 32-k tile = 512 contiguous,
// lane*8+j). ORPX: relative-pos bias expanded to [head][49 rows][64 cols] bf16
// so softmax bias loads are lane-consecutive (coalesced), not 13-stride gathers.
#define OQW   0
#define OQB   27648
#define OPW   27936
#define OPB   37152
#define ORPB  37248
#define ON1W  37760
#define ON1B  37856
#define ON2W  37952
#define ON2B  38048
#define OF1W  38144
#define OF1B  75008
#define OF2W  75392
#define OF2B  112256
#define ORPX  112352

// ============ prepass: detect input dtype, convert weights to bf16 ==========
__global__ __launch_bounds__(256) void k_detect_convert(
    const void* x,
    const void* qw, const void* qb, const void* pw, const void* pb, const void* rpb,
    const void* n1w, const void* n1b, const void* n2w, const void* n2b,
    const void* f1w, const void* f1b, const void* f2w, const void* f2b,
    int* flag, short* wb)
{
  __shared__ int cnt_sh;
  if (threadIdx.x == 0) cnt_sh = 0;
  __syncthreads();
  const unsigned* xw = (const unsigned*)x;
  int c = 0;
  for (int i = threadIdx.x; i < 1024; i += 256) {
    unsigned e = (xw[i] >> 7) & 0xFFu;      // exponent field of LOW bf16 half
    if (e >= 0x70u && e <= 0x8Fu) c++;
  }
  atomicAdd(&cnt_sh, c);
  __syncthreads();
  const int isb = (cnt_sh > 512) ? 1 : 0;   // bf16 data: ~1024; fp32 mantissa noise: ~128
  if (blockIdx.x == 0 && threadIdx.x == 0) *flag = isb;

  const void* srcs[13] = {qw, qb, pw, pb, rpb, n1w, n1b, n2w, n2b, f1w, f1b, f2w, f2b};
  const int   ns[13]   = {27648, 288, 9216, 96, 507, 96, 96, 96, 96, 36864, 384, 36864, 96};
  const int   offs[13] = {OQW, OQB, OPW, OPB, ORPB, ON1W, ON1B, ON2W, ON2B, OF1W, OF1B, OF2W, OF2B};
  const int gtid = blockIdx.x * 256 + threadIdx.x;
  for (int a = 0; a < 13; a++) {
    const void* s = srcs[a];
    for (int i = gtid; i < ns[a]; i += 64 * 256) {
      float val = isb ? bs2f(((const short*)s)[i]) : ((const float*)s)[i];
      int dst;
      if (a == 0 || a == 2 || a == 9) {
        // [C_out][96] row-major (qkv_w 288x96, proj_w 96x96, fc1_w 384x96)
        int col = i / 96, k = i - col * 96;
        int gt = col >> 4, l = col & 15;
        int kc = k >> 5, q = (k >> 3) & 3, j = k & 7;
        dst = ((gt * 3 + kc) << 9) + ((q * 16 + l) << 3) + j;
      } else if (a == 11) {
        // fc2_w [96][384] row-major
        int col = i / 384, k = i - col * 384;
        int nt = col >> 4, l = col & 15;
        int kt = k >> 5, q = (k >> 3) & 3, j = k & 7;
        dst = ((nt * 12 + kt) << 9) + ((q * 16 + l) << 3) + j;
      } else {
        dst = i;
      }
      wb[offs[a] + dst] = f2bs(val);
    }
  }

  // expanded RPB: [h][row 0..48][col 0..63] (cols>=49 zero)
  for (int i = gtid; i < 3 * 49 * 64; i += 64 * 256) {
    int hh = i / 3136, rem = i - hh * 3136;
    int row = rem >> 6, col = rem & 63;
    float val = 0.f;
    if (col < 49) {
      int ri = row / 7, rj = row - ri * 7, ci = col / 7, cj = col - ci * 7;
      int bidx = (ri - ci + 6) * 13 + (rj - cj + 6);
      val = isb ? bs2f(((const short*)rpb)[bidx * 3 + hh]) : ((const float*)rpb)[bidx * 3 + hh];
    }
    wb[ORPX + i] = f2bs(val);
  }
}

// ================= Kernel A: LN1 + shift/window + QKV + attn + proj =========
// one block per window (8192 blocks), 192 threads = 3 waves, wave h = head h.
// LDS 44544 B. xr written as bf16 (xr_idx layout). Single __syncthreads().
__global__ __launch_bounds__(192, 3) void k_attn_fused(
    const void* __restrict__ xg, const short* __restrict__ wb,
    const int* __restrict__ flag, void* __restrict__ xrout)
{
  __shared__ __align__(16) short smem[22272];

  const int isb = *flag;
  const int h = threadIdx.x >> 6;
  const int lane = threadIdx.x & 63;
  const int quad = lane >> 4, l15 = lane & 15;
  const int wi = blockIdx.x;
  const int bb = wi >> 8, wp = wi & 255, wh = wp >> 4, ww = wp & 15;

  short* Qh = smem + h * 5120;            // [64][40]
  short* Kh = Qh + 2560;                  // [64][40]
  short* Ph = smem + h * 5120;            // [64][72] overlays own Q/K
  short* Vh = smem + 15360 + h * 2304;    // [32][72]  (then O as [64][32])

  // LN gamma/beta for this lane's 24 channels
  float gwv[3][8], gbv[3][8];
  #pragma unroll
  for (int kc = 0; kc < 3; kc++) {
    s8v g = ld8(wb + ON1W + kc * 32 + quad * 8);
    s8v t = ld8(wb + ON1B + kc * 32 + quad * 8);
    #pragma unroll
    for (int j = 0; j < 8; j++) { gwv[kc][j] = bs2f(g[j]); gbv[kc][j] = bs2f(t[j]); }
  }

  // gather + LN1 into A-fragments (row = token, k = channel)
  s8v af[4][3];
  #pragma unroll
  for (int rt = 0; rt < 4; rt++) {
    int n = rt * 16 + l15; if (n > 48) n = 48;            // pad rows: dup row 48
    int ii = n / 7, jj = n - ii * 7;
    int hi = wh * 7 + ii + 3; if (hi >= 112) hi -= 112;   // roll(-3) gather
    int wj = ww * 7 + jj + 3; if (wj >= 112) wj -= 112;
    size_t rowoff = ((size_t)bb * 12544 + hi * 112 + wj) * 96;
    float v[3][8]; float sm = 0.f, sq = 0.f;
    #pragma unroll
    for (int kc = 0; kc < 3; kc++) {
      ld8d(xg, rowoff + kc * 32 + quad * 8, isb, v[kc]);
      #pragma unroll
      for (int j = 0; j < 8; j++) { sm += v[kc][j]; sq += v[kc][j] * v[kc][j]; }
    }
    sm += __shfl_xor(sm, 16); sm += __shfl_xor(sm, 32);   // reduce across quads
    sq += __shfl_xor(sq, 16); sq += __shfl_xor(sq, 32);
    float mean = sm * (1.f / 96.f);
    float var  = sq * (1.f / 96.f) - mean * mean;
    float rstd = rsqrtf(var + 1e-5f);
    #pragma unroll
    for (int kc = 0; kc < 3; kc++) {
      s8v o;
      #pragma unroll
      for (int j = 0; j < 8; j++) o[j] = f2bs((v[kc][j] - mean) * rstd * gwv[kc][j] + gbv[kc][j]);
      af[rt][kc] = o;
    }
  }

  // QKV gemm: wave h computes head h's Q,K,V (2 col-tiles each)
  const float qscale = 0.1767766952966369f;  // 32^-0.5 folded into Q
  #pragma unroll
  for (int s = 0; s < 3; s++) {
    #pragma unroll
    for (int nt = 0; nt < 2; nt++) {
      int col = s * 96 + h * 32 + nt * 16 + l15;
      const short* tb = wb + OQW + (size_t)(s * 6 + h * 2 + nt) * 1536;
      s8v b0 = ld8(tb + lane * 8), b1 = ld8(tb + 512 + lane * 8), b2 = ld8(tb + 1024 + lane * 8);
      float bias = bs2f(wb[OQB + col]);
      #pragma unroll
      for (int rt = 0; rt < 4; rt++) {
        f4v acc = {0.f, 0.f, 0.f, 0.f};
        acc = __builtin_amdgcn_mfma_f32_16x16x32_bf16(af[rt][0], b0, acc, 0, 0, 0);
        acc = __builtin_amdgcn_mfma_f32_16x16x32_bf16(af[rt][1], b1, acc, 0, 0, 0);
        acc = __builtin_amdgcn_mfma_f32_16x16x32_bf16(af[rt][2], b2, acc, 0, 0, 0);
        #pragma unroll
        for (int r = 0; r < 4; r++) {
          int tok = rt * 16 + quad * 4 + r;          // C-layout: row=quad*4+r, col=l15
          float val = acc[r] + bias;
          int cc = nt * 16 + l15;
          if (s == 0)      Qh[tok * 40 + cc] = f2bs(val * qscale);
          else if (s == 1) Kh[tok * 40 + cc] = f2bs(val);
          else             Vh[cc * 72 + tok] = f2bs(val);   // transposed
        }
      }
    }
  }
  wave_lds_fence();   // Q/K/V stores are per-wave slabs

  s8v qa[4], kb[4], vf[2][2];
  #pragma unroll
  for (int t = 0; t < 4; t++) {
    qa[t] = *(const s8v*)&Qh[(t * 16 + l15) * 40 + quad * 8];
    kb[t] = *(const s8v*)&Kh[(t * 16 + l15) * 40 + quad * 8];
  }
  #pragma unroll
  for (int nt = 0; nt < 2; nt++)
    #pragma unroll
    for (int kc = 0; kc < 2; kc++)
      vf[nt][kc] = *(const s8v*)&Vh[(nt * 16 + l15) * 72 + kc * 32 + quad * 8];

  // mask geometry per key column
  int crid[4]; bool cv[4];
  #pragma unroll
  for (int nt = 0; nt < 4; nt++) {
    int col = nt * 16 + l15;
    cv[nt] = (col < 49);
    int ki = col / 7, kj = col - ki * 7;
    crid[nt] = rgn(wh * 7 + ki) * 3 + rgn(ww * 7 + kj);
  }

  // QK^T + softmax per row-tile. Bias from expanded table: lane-consecutive.
  #pragma unroll
  for (int rt = 0; rt < 4; rt++) {
    f4v sc4[4];
    #pragma unroll
    for (int nt = 0; nt < 4; nt++) {
      f4v z = {0.f, 0.f, 0.f, 0.f};
      sc4[nt] = __builtin_amdgcn_mfma_f32_16x16x32_bf16(qa[rt], kb[nt], z, 0, 0, 0);
    }
    #pragma unroll
    for (int rr = 0; rr < 4; rr++) {
      int row = rt * 16 + quad * 4 + rr;
      bool vr = (row < 49);
      int ri = row / 7, rj = row - ri * 7;
      int rrid = rgn(wh * 7 + ri) * 3 + rgn(ww * 7 + rj);
      int rbase = ORPX + h * 3136 + ((row < 49) ? row : 48) * 64;   // clamp: stay in slab
      float vals[4];
      float m = -1e30f;
      #pragma unroll
      for (int nt = 0; nt < 4; nt++) {
        float bias = bs2f(wb[rbase + nt * 16 + l15]);   // coalesced
        float sv;
        if (vr && cv[nt]) {
          sv = sc4[nt][rr] + bias + ((rrid == crid[nt]) ? 0.f : -100.f);
        } else {
          sv = vr ? -1e30f : 0.f;
        }
        vals[nt] = sv;
        m = fmaxf(m, sv);
      }
      #pragma unroll
      for (int o = 1; o < 16; o <<= 1) m = fmaxf(m, __shfl_xor(m, o));
      float sum = 0.f;
      #pragma unroll
      for (int nt = 0; nt < 4; nt++) { vals[nt] = __expf(vals[nt] - m); sum += vals[nt]; }
      #pragma unroll
      for (int o = 1; o < 16; o <<= 1) sum += __shfl_xor(sum, o);
      float inv = 1.f / sum;
      #pragma unroll
      for (int nt = 0; nt < 4; nt++)
        Ph[row * 72 + nt * 16 + l15] = f2bs(vals[nt] * inv);
    }
  }
  wave_lds_fence();   // P per-wave

  // PV
  s8v pf[4][2];
  #pragma unroll
  for (int rt = 0; rt < 4; rt++)
    #pragma unroll
    for (int kc = 0; kc < 2; kc++)
      pf[rt][kc] = *(const s8v*)&Ph[(rt * 16 + l15) * 72 + kc * 32 + quad * 8];
  short* Oh = Vh;   // [64][32], own wave's region
  #pragma unroll
  for (int rt = 0; rt < 4; rt++) {
    #pragma unroll
    for (int nt = 0; nt < 2; nt++) {
      f4v acc = {0.f, 0.f, 0.f, 0.f};
      acc = __builtin_amdgcn_mfma_f32_16x16x32_bf16(pf[rt][0], vf[nt][0], acc, 0, 0, 0);
      acc = __builtin_amdgcn_mfma_f32_16x16x32_bf16(pf[rt][1], vf[nt][1], acc, 0, 0, 0);
      #pragma unroll
      for (int r = 0; r < 4; r++) {
        int tok = rt * 16 + quad * 4 + r;
        Oh[tok * 32 + nt * 16 + l15] = f2bs(acc[r]);
      }
    }
  }
  __syncthreads();   // the ONE true cross-wave barrier: proj reads all heads' O

  // proj: A = O (k = 3 heads x 32), wave h computes out cols h*32..+31
  s8v of[4][3];
  #pragma unroll
  for (int rt = 0; rt < 4; rt++)
    #pragma unroll
    for (int kc = 0; kc < 3; kc++)
      of[rt][kc] = *(const s8v*)&smem[15360 + kc * 2304 + (rt * 16 + l15) * 32 + quad * 8];
  short* xrs = (short*)xrout;
  #pragma unroll
  for (int nt = 0; nt < 2; nt++) {
    int col = h * 32 + nt * 16 + l15;
    const short* tb = wb + OPW + (size_t)(h * 2 + nt) * 1536;
    s8v b0 = ld8(tb + lane * 8), b1 = ld8(tb + 512 + lane * 8), b2 = ld8(tb + 1024 + lane * 8);
    float bias = bs2f(wb[OPB + col]);
    #pragma unroll
    for (int rt = 0; rt < 4; rt++) {
      f4v acc = {0.f, 0.f, 0.f, 0.f};
      acc = __builtin_amdgcn_mfma_f32_16x16x32_bf16(of[rt][0], b0, acc, 0, 0, 0);
      acc = __builtin_amdgcn_mfma_f32_16x16x32_bf16(of[rt][1], b1, acc, 0, 0, 0);
      acc = __builtin_amdgcn_mfma_f32_16x16x32_bf16(of[rt][2], b2, acc, 0, 0, 0);
      #pragma unroll
      for (int r = 0; r < 4; r++) {
        int tok = rt * 16 + quad * 4 + r;
        if (tok < 49) {
          int ii = tok / 7, jj = tok - ii * 7;
          int hi = wh * 7 + ii + 3; if (hi >= 112) hi -= 112;  // reverse + roll(+3)
          int wj = ww * 7 + jj + 3; if (wj >= 112) wj -= 112;
          size_t drow = (size_t)bb * 12544 + hi * 112 + wj;
          xrs[xr_idx(drow, col, isb)] = f2bs(acc[r] + bias);   // bf16 xr
        }
      }
    }
  }
}

// ================= Kernel B: LN2 + fc1 + GELU + fc2 + residuals =============
// 256 threads = 4 waves, each wave owns 64 rows, fully independent -> zero
// barriers. fc1/fc2 in two K-halves of 192 -> h_sh [4][16][200] = 25600 B LDS.
// launch_bounds(256,4): VGPR cap 128 (no spill). xr read ONCE as bf16 (LN2),
// carried in v[] to the epilogue; epilogue reads only x. Per-rt order:
// xr reads (top) ... out writes (bottom) of the SAME rows -> the isb=0 in-slot
// xr overlay is read-before-overwrite within each wave's lockstep.
__global__ __launch_bounds__(256, 4) void k_mlp(
    const void* xrv, const void* __restrict__ xg, const short* __restrict__ wb,
    const int* __restrict__ flag, void* outv)
{
  __shared__ __align__(16) short h_sh[4][16][200];   // per-wave 16-row, 192-col half

  const int isb = *flag;
  const int wave = threadIdx.x >> 6, lane = threadIdx.x & 63;
  const int quad = lane >> 4, l15 = lane & 15;
  const size_t m0 = (size_t)blockIdx.x * 256 + (size_t)wave * 64;
  const short* xrs = (const short*)xrv;

  // keep LN gamma/beta as bf16 (24 VGPRs, not 48 floats)
  s8v gw[3], gb[3];
  #pragma unroll
  for (int kc = 0; kc < 3; kc++) {
    gw[kc] = ld8(wb + ON2W + kc * 32 + quad * 8);
    gb[kc] = ld8(wb + ON2B + kc * 32 + quad * 8);
  }

  for (int rt = 0; rt < 4; rt++) {
    // ---- LN2 of this tile's 16 rows (row = l15); v[] stays live to epilogue ----
    size_t grow0 = m0 + rt * 16 + l15;
    float v[3][8]; float sm = 0.f, sq = 0.f;
    #pragma unroll
    for (int kc = 0; kc < 3; kc++) {
      s8v xv = ld8(xrs + xr_idx(grow0, kc * 32 + quad * 8, isb));
      #pragma unroll
      for (int j = 0; j < 8; j++) {
        v[kc][j] = bs2f(xv[j]);
        sm += v[kc][j]; sq += v[kc][j] * v[kc][j];
      }
    }
    sm += __shfl_xor(sm, 16); sm += __shfl_xor(sm, 32);
    sq += __shfl_xor(sq, 16); sq += __shfl_xor(sq, 32);
    float mean = sm * (1.f / 96.f);
    float var  = sq * (1.f / 96.f) - mean * mean;
    float rstd = rsqrtf(var + 1e-5f);
    s8v a2[3];
    #pragma unroll
    for (int kc = 0; kc < 3; kc++) {
      s8v o;
      #pragma unroll
      for (int j = 0; j < 8; j++)
        o[j] = f2bs((v[kc][j] - mean) * rstd * bs2f(gw[kc][j]) + bs2f(gb[kc][j]));
      a2[kc] = o;
    }

    f4v acc6[6];
    #pragma unroll
    for (int nt = 0; nt < 6; nt++) { f4v z = {0.f, 0.f, 0.f, 0.f}; acc6[nt] = z; }

    // ---- two K-halves: fc1(192 cols)+GELU -> h_sh, then fc2 partial ----
    for (int half = 0; half < 2; half++) {
      for (int nt = 0; nt < 12; nt++) {
        int col = half * 192 + nt * 16 + l15;
        const short* tb = wb + OF1W + (size_t)(half * 12 + nt) * 1536;
        s8v b0 = ld8(tb + lane * 8), b1 = ld8(tb + 512 + lane * 8), b2 = ld8(tb + 1024 + lane * 8);
        float bias = bs2f(wb[OF1B + col]);
        f4v acc = {0.f, 0.f, 0.f, 0.f};
        acc = __builtin_amdgcn_mfma_f32_16x16x32_bf16(a2[0], b0, acc, 0, 0, 0);
        acc = __builtin_amdgcn_mfma_f32_16x16x32_bf16(a2[1], b1, acc, 0, 0, 0);
        acc = __builtin_amdgcn_mfma_f32_16x16x32_bf16(a2[2], b2, acc, 0, 0, 0);
        #pragma unroll
        for (int r = 0; r < 4; r++)
          h_sh[wave][quad * 4 + r][nt * 16 + l15] = f2bs(gelu_f(acc[r] + bias));
      }
      wave_lds_fence();   // h1 half visible to own wave's cross-lane reads

      // fc2 partial: A from h_sh (per-kc load), B coalesced from L2
      for (int kc = 0; kc < 6; kc++) {
        s8v ha = *(const s8v*)&h_sh[wave][l15][kc * 32 + quad * 8];
        #pragma unroll
        for (int nt = 0; nt < 6; nt++) {
          s8v b = ld8(wb + OF2W + (size_t)(nt * 12 + half * 6 + kc) * 512 + lane * 8);
          acc6[nt] = __builtin_amdgcn_mfma_f32_16x16x32_bf16(ha, b, acc6[nt], 0, 0, 0);
        }
      }
      wave_lds_fence();   // ha reads drained before next half overwrites h_sh
    }

    // ---- transpose acc via per-wave f32 LDS tile [16][100] = 6400 B slice ----
    float* ot = (float*)&h_sh[wave][0][0];
    #pragma unroll
    for (int nt = 0; nt < 6; nt++) {
      float bias = bs2f(wb[OF2B + nt * 16 + l15]);
      #pragma unroll
      for (int r = 0; r < 4; r++)
        ot[(quad * 4 + r) * 100 + nt * 16 + l15] = acc6[nt][r] + bias;
    }
    wave_lds_fence();   // f32 tile visible for cross-lane vector reads

    // ---- epilogue: thread (quad,l15) owns row l15, chunks c0 = j*32+quad*8
    // (exactly the elements whose xr this thread loaded -> v[j] carried).
    #pragma unroll
    for (int j = 0; j < 3; j++) {
      int c0 = j * 32 + quad * 8;
      float vx[8], vo[8];
      ld8d(xg, grow0 * 96 + c0, isb, vx);
      #pragma unroll
      for (int e = 0; e < 8; e++) vo[e] = ot[l15 * 100 + c0 + e] + vx[e] + v[j][e];
      st8d(outv, grow0 * 96 + c0, isb, vo);
    }
    wave_lds_fence();   // ot reads drained before next rt's fc1 writes (WAR)
  }
}

extern "C" void kernel_launch(void* const* d_in, const int* in_sizes, int n_in,
                              void* d_out, int out_size, void* d_ws, size_t ws_size,
                              hipStream_t stream) {
  int*   flag = (int*)d_ws;
  short* wb   = (short*)d_ws + 8;   // bf16 weight table, byte offset 16

  k_detect_convert<<<64, 256, 0, stream>>>(
      d_in[0],
      d_in[3], d_in[4], d_in[5], d_in[6], d_in[7],
      d_in[1], d_in[2], d_in[8], d_in[9],
      d_in[10], d_in[11], d_in[12], d_in[13],
      flag, wb);
  k_attn_fused<<<32 * 256, 192, 0, stream>>>(d_in[0], wb, flag, d_out);
  k_mlp<<<NTOK / 256, 256, 0, stream>>>(d_out, d_in[0], wb, flag, d_out);
}